// Round 5
// baseline (594.187 us; speedup 1.0000x reference)
//
#include <hip/hip_runtime.h>
#include <hip/hip_cooperative_groups.h>
#include <cmath>

namespace cg = cooperative_groups;

#define NN 10000
#define NE 160000
#define INV_SQRT_C 0.08838834764831845f   // 1/sqrt(128)
#define INV_SQRT3F 0.5773502691896258f

typedef _Float16 f16x8 __attribute__((ext_vector_type(8)));
typedef _Float16 f16x4 __attribute__((ext_vector_type(4)));
typedef _Float16 f16x2 __attribute__((ext_vector_type(2)));
typedef float    f32x4 __attribute__((ext_vector_type(4)));

__device__ __forceinline__ float silu_f(float x) {
  return x / (1.f + __expf(-x));
}

// ---------------------------------------------------------------------------
// prep superkernel: blocks [0,768) = weight conversion (6 jobs x 128 blocks),
// blocks [768,2018) = node pre-pass (625 s-blocks + 625 v-blocks).
// Inner code verbatim from the verified round-4 kernels; only the block-index
// plumbing changed. Single launch => wconv fills CUs during node tail.
// ---------------------------------------------------------------------------
__device__ __forceinline__ void wconv_one(
    int bx, const float* __restrict__ src, _Float16* __restrict__ dst,
    int Korig, int Kpad, int N, float scale, int P) {
  int total = Kpad * N;
  for (int t = bx * 256 + threadIdx.x; t < total; t += 128 * 256) {
    int n = t % N;
    int k = t / N;
    int kb = k >> 5, kk = k & 31;
    int sub = n & (P - 1);
    int n_l = (n & ~(P - 1)) | ((sub & 15) * (P >> 4) + (sub >> 4));
    float v = (k < Korig) ? src[(size_t)k * N + n_l] * scale : 0.f;
    dst[((size_t)(kb * N + n) << 5) + kk] = (_Float16)v;
  }
}

__global__ __launch_bounds__(256) void prep(
    const float* __restrict__ s0, const float* __restrict__ s1,
    const float* __restrict__ s2, const float* __restrict__ s3,
    const float* __restrict__ s4, const float* __restrict__ s5,
    _Float16* __restrict__ d0, _Float16* __restrict__ d1,
    _Float16* __restrict__ d2, _Float16* __restrict__ d3,
    _Float16* __restrict__ d4, _Float16* __restrict__ d5,
    const float* __restrict__ feats,
    const float* __restrict__ W_up0, const float* __restrict__ W_skip0,
    const float* __restrict__ W_down,
    const float* __restrict__ W_up1, const float* __restrict__ W_skip1,
    _Float16* __restrict__ UPH, _Float16* __restrict__ DOWNH,
    float* __restrict__ out_sc) {
  __shared__ float ls[16 * 384];
  const int b = blockIdx.x;
  const int t = threadIdx.x;

  if (b < 768) {
    const int job = b >> 7, bx = b & 127;
    switch (job) {
      case 0: wconv_one(bx, s0, d0, 136, 160, 256, 0.08574929257125442f, 64); break;
      case 1: wconv_one(bx, s1, d1, 256, 256, 256, 0.0625f, 64); break;
      case 2: wconv_one(bx, s2, d2, 256, 256, 256, 0.0625f, 64); break;
      case 3: wconv_one(bx, s3, d3, 256, 256, 512, 0.0625f, 32); break;
      case 4: wconv_one(bx, s4, d4, 256, 256, 128, 1.0f / 256.0f, 32); break;
      default: wconv_one(bx, s5, d5, 256, 256, 128, 1.0f / 256.0f, 32); break;
    }
    return;
  }

  const int nb = b - 768;
  if (nb < 625) {
    const int n0 = nb * 16;
    for (int f = t; f < 16 * 128; f += 256) {
      int r = f >> 7, c = f & 127;
      ls[r * 128 + c] = feats[(size_t)(n0 + r) * 512 + c];
    }
    __syncthreads();
    {
      int j = t & 127, g = t >> 7;  // 8 nodes per group
      float au[8] = {0, 0, 0, 0, 0, 0, 0, 0};
      float ak[8] = {0, 0, 0, 0, 0, 0, 0, 0};
      for (int i = 0; i < 128; ++i) {
        float wu = W_up0[(size_t)i * 128 + j];
        float wk = W_skip0[(size_t)i * 128 + j];
#pragma unroll
        for (int r = 0; r < 8; ++r) {
          float s = ls[(g * 8 + r) * 128 + i];
          au[r] += s * wu;
          ak[r] += s * wk;
        }
      }
#pragma unroll
      for (int r = 0; r < 8; ++r) {
        int n = n0 + g * 8 + r;
        UPH[(size_t)n * 512 + j] = (_Float16)(au[r] * INV_SQRT_C);
        out_sc[(size_t)n * 512 + j] = ak[r] * INV_SQRT_C;
      }
    }
    {
      int j = t & 63, g = t >> 6;  // 4 nodes per group
      float ad[4] = {0, 0, 0, 0};
      for (int i = 0; i < 128; ++i) {
        float wd = W_down[(size_t)i * 64 + j];
#pragma unroll
        for (int r = 0; r < 4; ++r) ad[r] += ls[(g * 4 + r) * 128 + i] * wd;
      }
#pragma unroll
      for (int r = 0; r < 4; ++r)
        DOWNH[(size_t)(n0 + g * 4 + r) * 64 + j] = (_Float16)(ad[r] * INV_SQRT_C);
    }
  } else {
    const int n0 = (nb - 625) * 16;
    for (int f = t; f < 16 * 384; f += 256) {
      int r = f / 384, c = f % 384;
      ls[r * 384 + c] = feats[(size_t)(n0 + r) * 512 + 128 + c];
    }
    __syncthreads();
    int j = t & 127, g = t >> 7;
    float au[8][3], ak[8][3];
#pragma unroll
    for (int r = 0; r < 8; ++r)
#pragma unroll
      for (int c = 0; c < 3; ++c) { au[r][c] = 0.f; ak[r][c] = 0.f; }
    for (int i = 0; i < 128; ++i) {
      float wu = W_up1[(size_t)i * 128 + j];
      float wk = W_skip1[(size_t)i * 128 + j];
#pragma unroll
      for (int r = 0; r < 8; ++r) {
#pragma unroll
        for (int c = 0; c < 3; ++c) {
          float v = ls[(g * 8 + r) * 384 + i * 3 + c];
          au[r][c] += v * wu;
          ak[r][c] += v * wk;
        }
      }
    }
#pragma unroll
    for (int r = 0; r < 8; ++r) {
      int n = n0 + g * 8 + r;
#pragma unroll
      for (int c = 0; c < 3; ++c) {
        UPH[(size_t)n * 512 + 128 + j * 3 + c] = (_Float16)(au[r][c] * INV_SQRT_C);
        out_sc[(size_t)n * 512 + 128 + j * 3 + c] = ak[r][c] * INV_SQRT_C;
      }
    }
  }
}

// ---------------------------------------------------------------------------
// Cooperative CSR kernel: zero -> count -> scan -> fill with grid.sync()
// between phases. 256 blocks x 256 threads (1 block/CU, trivially
// co-resident). EIDX stores the SENDER-SORTED POSITION of each receiver-CSR
// edge (same semantics as round 4). Replaces memset + 3 kernel launches.
// ---------------------------------------------------------------------------
__global__ __launch_bounds__(256) void k_csr(
    const int* __restrict__ edge_index,
    int* CNT, int* CNT2,
    int* __restrict__ OFF, int* __restrict__ CUR,
    int* __restrict__ OFF2, int* __restrict__ CUR2,
    int* __restrict__ EIDX, int* __restrict__ SIDX) {
  cg::grid_group grid = cg::this_grid();
  const int t = threadIdx.x;
  const int gt = blockIdx.x * 256 + t;
  const int gs = gridDim.x * 256;

  // phase 0: zero counters
  for (int i = gt; i < NN; i += gs) { CNT[i] = 0; CNT2[i] = 0; }
  grid.sync();

  // phase 1: count both endpoints
  for (int e = gt; e < NE; e += gs) {
    int2 sr = *(const int2*)&edge_index[(size_t)e * 2];
    atomicAdd(&CNT[sr.y], 1);    // receiver
    atomicAdd(&CNT2[sr.x], 1);   // sender
  }
  grid.sync();

  // phase 2: two exclusive scans (block 0: receiver, block 1: sender).
  // Two-pass per thread (sum, then re-emit) — C stays L2-hot.
  if (blockIdx.x < 2) {
    const int* C = (blockIdx.x == 0) ? CNT : CNT2;
    int* O = (blockIdx.x == 0) ? OFF : OFF2;
    int* U = (blockIdx.x == 0) ? CUR : CUR2;
    __shared__ int ts[256];
    const int base = t * 40;           // 256*40 = 10240 >= NN
    int s = 0;
    for (int i = 0; i < 40; ++i) {
      int idx = base + i;
      if (idx < NN) s += C[idx];
    }
    ts[t] = s;
    __syncthreads();
    for (int off = 1; off < 256; off <<= 1) {
      int v = (t >= off) ? ts[t - off] : 0;
      __syncthreads();
      ts[t] += v;
      __syncthreads();
    }
    int run = (t > 0) ? ts[t - 1] : 0;
    for (int i = 0; i < 40; ++i) {
      int idx = base + i;
      if (idx < NN) {
        O[idx] = run;
        U[idx] = run;
        run += C[idx];
      }
    }
    if (t == 255) O[NN] = ts[255];
  }
  grid.sync();

  // phase 3: fill both orderings
  for (int e = gt; e < NE; e += gs) {
    int2 sr = *(const int2*)&edge_index[(size_t)e * 2];
    int ps = atomicAdd(&CUR2[sr.x], 1);  // sender-sorted position
    SIDX[ps] = e;
    int pr = atomicAdd(&CUR[sr.y], 1);   // receiver-CSR slot
    EIDX[pr] = ps;                       // gather reads MIDs[ps]
  }
}

// ---------------------------------------------------------------------------
// Fused edge kernel — round-0 verified structure (HA/HB ping-pong, SW/SP
// separate, original barrier schedule; 64 KB LDS, 2 blocks/CU, 128 VGPR).
// MIDs rows indexed by sender-sorted position (e0 + row) => contiguous per
// block. VERBATIM from round 4 (257.6 us, absmax 0.002).
// ---------------------------------------------------------------------------
__device__ __forceinline__ void mlp_layer_256(
    const _Float16* In, _Float16* Out, const _Float16* __restrict__ Wz,
    int m, int g, int wv) {
  f32x4 acc[4][4];
  f32x4 zero4 = {0.f, 0.f, 0.f, 0.f};
#pragma unroll
  for (int rt = 0; rt < 4; ++rt)
#pragma unroll
    for (int ct = 0; ct < 4; ++ct) acc[rt][ct] = zero4;

#pragma unroll
  for (int kb = 0; kb < 8; ++kb) {
    f16x8 a[4], b[4];
#pragma unroll
    for (int rt = 0; rt < 4; ++rt) {
      int row = rt * 16 + m;
      a[rt] = *(const f16x8*)&In[row * 256 + (((kb * 2 + (g >> 1)) ^ m) << 4) + (g & 1) * 8];
    }
#pragma unroll
    for (int ct = 0; ct < 4; ++ct)
      b[ct] = *(const f16x8*)&Wz[((size_t)(kb * 256 + wv * 64 + ct * 16 + m) << 5) + g * 8];
#pragma unroll
    for (int rt = 0; rt < 4; ++rt)
#pragma unroll
      for (int ct = 0; ct < 4; ++ct)
        acc[rt][ct] = __builtin_amdgcn_mfma_f32_16x16x32_f16(a[rt], b[ct], acc[rt][ct], 0, 0, 0);
  }
#pragma unroll
  for (int rt = 0; rt < 4; ++rt)
#pragma unroll
    for (int q = 0; q < 4; ++q) {
      int row = rt * 16 + g * 4 + q;
      f16x4 pk;
#pragma unroll
      for (int ct = 0; ct < 4; ++ct) pk[ct] = (_Float16)silu_f(acc[rt][ct][q]);
      int blk = (wv * 4 + (m >> 2)) ^ (row & 15);
      *(f16x4*)&Out[row * 256 + (blk << 4) + (m & 3) * 4] = pk;
    }
}

__global__ __launch_bounds__(256, 2) void edge_mlp(
    const float* __restrict__ edge_attrs,
    const float* __restrict__ edge_feats,
    const int* __restrict__ edge_index,
    const int* __restrict__ SIDX,
    const _Float16* __restrict__ DOWNH,
    const _Float16* __restrict__ UPH,
    const _Float16* __restrict__ W0h, const _Float16* __restrict__ W1h,
    const _Float16* __restrict__ W2h, const _Float16* __restrict__ W3h,
    const _Float16* __restrict__ WL0h, const _Float16* __restrict__ WL1h,
    _Float16* __restrict__ MIDs) {
  __shared__ _Float16 HA[64 * 256];
  __shared__ _Float16 HB[64 * 256];

  const int tid = threadIdx.x;
  const int lane = tid & 63;
  const int wv = tid >> 6;
  const int m = lane & 15;
  const int g = lane >> 4;
  const int e0 = blockIdx.x * 64;
  const int nw = wv * 64;

  int el_r[4], snd_r[4], rcv_r[4];
#pragma unroll
  for (int rt = 0; rt < 4; ++rt) {
    el_r[rt] = SIDX[e0 + rt * 16 + m];
    int2 sr = *(const int2*)&edge_index[(size_t)el_r[rt] * 2];
    snd_r[rt] = sr.x;
    rcv_r[rt] = sr.y;
  }

  f32x4 zero4 = {0.f, 0.f, 0.f, 0.f};
  f16x8 zf = {0, 0, 0, 0, 0, 0, 0, 0};

  // ---------------- layer 0: aug(136, padded 160) -> h1 (HA)
  {
    f32x4 acc[4][4];
#pragma unroll
    for (int rt = 0; rt < 4; ++rt)
#pragma unroll
      for (int ct = 0; ct < 4; ++ct) acc[rt][ct] = zero4;

#pragma unroll
    for (int kb = 0; kb < 5; ++kb) {
      const int k0 = kb * 32 + g * 8;
      f16x8 a[4], b[4];
#pragma unroll
      for (int rt = 0; rt < 4; ++rt) {
        if (k0 == 0) {
          const float* ef = &edge_feats[(size_t)el_r[rt] * 8];
          float4 f0 = *(const float4*)ef;
          float4 f1 = *(const float4*)(ef + 4);
          f16x8 av;
          av[0] = (_Float16)f0.x; av[1] = (_Float16)f0.y;
          av[2] = (_Float16)f0.z; av[3] = (_Float16)f0.w;
          av[4] = (_Float16)f1.x; av[5] = (_Float16)f1.y;
          av[6] = (_Float16)f1.z; av[7] = (_Float16)f1.w;
          a[rt] = av;
        } else if (k0 < 72) {
          a[rt] = *(const f16x8*)&DOWNH[(size_t)snd_r[rt] * 64 + (k0 - 8)];
        } else if (k0 < 136) {
          a[rt] = *(const f16x8*)&DOWNH[(size_t)rcv_r[rt] * 64 + (k0 - 72)];
        } else {
          a[rt] = zf;
        }
      }
#pragma unroll
      for (int ct = 0; ct < 4; ++ct)
        b[ct] = *(const f16x8*)&W0h[((size_t)(kb * 256 + nw + ct * 16 + m) << 5) + g * 8];
#pragma unroll
      for (int rt = 0; rt < 4; ++rt)
#pragma unroll
        for (int ct = 0; ct < 4; ++ct)
          acc[rt][ct] = __builtin_amdgcn_mfma_f32_16x16x32_f16(a[rt], b[ct], acc[rt][ct], 0, 0, 0);
    }
#pragma unroll
    for (int rt = 0; rt < 4; ++rt)
#pragma unroll
      for (int q = 0; q < 4; ++q) {
        int row = rt * 16 + g * 4 + q;
        f16x4 pk;
#pragma unroll
        for (int ct = 0; ct < 4; ++ct) pk[ct] = (_Float16)silu_f(acc[rt][ct][q]);
        int blk = (wv * 4 + (m >> 2)) ^ (row & 15);
        *(f16x4*)&HA[row * 256 + (blk << 4) + (m & 3) * 4] = pk;
      }
  }
  __syncthreads();

  mlp_layer_256(HA, HB, W1h, m, g, wv);   // layer 1: h1 -> h2
  __syncthreads();
  mlp_layer_256(HB, HA, W2h, m, g, wv);   // layer 2: h2 -> h3 (HA stays live)
  __syncthreads();

  // ================= epilogue =================
  _Float16* SW = HB;             // 64 x 128 fp16, tpw quarter
  _Float16* SP = HB + 64 * 128;  // 64 x 128 fp16, TP'd A-matrix

  const int e_loc = lane;
  const int ers = (e_loc ^ (e_loc >> 3)) & 7;
  const int elc = SIDX[e0 + e_loc];
  const int snd_e = edge_index[(size_t)elc * 2];
  const _Float16* uprow = &UPH[(size_t)snd_e * 512];

  // quarter GEMM into caller-provided acc buffer
  auto qgemm = [&](int qbase, f32x4 (&accq)[4][2]) {
#pragma unroll
    for (int rt = 0; rt < 4; ++rt)
#pragma unroll
      for (int ct = 0; ct < 2; ++ct) accq[rt][ct] = zero4;
#pragma unroll
    for (int kb = 0; kb < 8; ++kb) {
      f16x8 a[4], b[2];
#pragma unroll
      for (int rt = 0; rt < 4; ++rt) {
        int row = rt * 16 + m;
        a[rt] = *(const f16x8*)&HA[row * 256 + (((kb * 2 + (g >> 1)) ^ m) << 4) + (g & 1) * 8];
      }
#pragma unroll
      for (int ct = 0; ct < 2; ++ct)
        b[ct] = *(const f16x8*)&W3h[((size_t)(kb * 512 + qbase + wv * 32 + ct * 16 + m) << 5) + g * 8];
#pragma unroll
      for (int rt = 0; rt < 4; ++rt)
#pragma unroll
        for (int ct = 0; ct < 2; ++ct)
          accq[rt][ct] = __builtin_amdgcn_mfma_f32_16x16x32_f16(a[rt], b[ct], accq[rt][ct], 0, 0, 0);
    }
  };

  auto sw_write = [&](const f32x4 (&accq)[4][2]) {
#pragma unroll
    for (int rt = 0; rt < 4; ++rt)
#pragma unroll
      for (int r4 = 0; r4 < 4; ++r4) {
        int row = rt * 16 + g * 4 + r4;
        int rs = (row ^ (row >> 3)) & 7;
        f16x2 pk;
        pk[0] = (_Float16)accq[rt][0][r4];
        pk[1] = (_Float16)accq[rt][1][r4];
        int blk = ((wv * 2 + (m >> 3)) ^ rs) & 7;
        *(f16x2*)&SW[row * 128 + (blk << 4) + (m & 7) * 2] = pk;
      }
  };

  auto fold = [&](const _Float16* __restrict__ WLh, int qpart, f32x4 (&P)[4][2]) {
#pragma unroll
    for (int rt = 0; rt < 4; ++rt)
#pragma unroll
      for (int ct = 0; ct < 2; ++ct) P[rt][ct] = zero4;
#pragma unroll
    for (int kb = 0; kb < 4; ++kb) {
      f16x8 a[4], b[2];
#pragma unroll
      for (int rt = 0; rt < 4; ++rt) {
        int row = rt * 16 + m;
        int rs = (row ^ (row >> 3)) & 7;
        a[rt] = *(const f16x8*)&SP[row * 128 + ((((kb * 2 + (g >> 1)) ^ rs) & 7) << 4) + (g & 1) * 8];
      }
#pragma unroll
      for (int ct = 0; ct < 2; ++ct)
        b[ct] = *(const f16x8*)&WLh[((size_t)((qpart * 4 + kb) * 128 + wv * 32 + ct * 16 + m) << 5) + g * 8];
#pragma unroll
      for (int rt = 0; rt < 4; ++rt)
#pragma unroll
        for (int ct = 0; ct < 2; ++ct)
          P[rt][ct] = __builtin_amdgcn_mfma_f32_16x16x32_f16(a[rt], b[ct], P[rt][ct], 0, 0, 0);
    }
  };

  auto tp_xs = [&]() {
#pragma unroll
    for (int cch = 0; cch < 4; ++cch) {
      int ib = nw / 2 + cch * 8;
      int blk = ((ib >> 4) ^ ers) & 7;
      int off = e_loc * 128 + (blk << 4) + (ib & 15);
      f16x8 swv = *(const f16x8*)&SW[off];
      f16x8 upv = *(const f16x8*)&uprow[ib];
      f16x8 pr = swv * upv;
      *(f16x8*)&SP[off] = pr;
    }
  };

  _Float16 xvb[96];
  auto load_xv = [&]() {
#pragma unroll
    for (int u = 0; u < 12; ++u) {
      f16x8 t = *(const f16x8*)&uprow[128 + wv * 96 + u * 8];
#pragma unroll
      for (int z = 0; z < 8; ++z) xvb[u * 8 + z] = t[z];
    }
  };

  auto tp_w4 = [&]() {
    float4 ea = *(const float4*)&edge_attrs[(size_t)elc * 4];
#pragma unroll
    for (int cch = 0; cch < 4; ++cch) {
      int ib = nw / 2 + cch * 8;
      int blk = ((ib >> 4) ^ ers) & 7;
      int off = e_loc * 128 + (blk << 4) + (ib & 15);
      f16x8 swv = *(const f16x8*)&SW[off];
      f16x8 outv;
#pragma unroll
      for (int z = 0; z < 8; ++z) {
        int k = cch * 8 + z;
        float d = (float)xvb[k * 3] * ea.y + (float)xvb[k * 3 + 1] * ea.z +
                  (float)xvb[k * 3 + 2] * ea.w;
        outv[z] = (_Float16)((float)swv[z] * d);
      }
      *(f16x8*)&SP[off] = outv;
    }
  };

  auto tp_w3 = [&](int c) {
#pragma unroll
    for (int cch = 0; cch < 4; ++cch) {
      int ib = nw / 2 + cch * 8;
      int blk = ((ib >> 4) ^ ers) & 7;
      int off = e_loc * 128 + (blk << 4) + (ib & 15);
      f16x8 swv = *(const f16x8*)&SW[off];
      f16x8 outv;
#pragma unroll
      for (int z = 0; z < 8; ++z) {
        int k = cch * 8 + z;
        outv[z] = swv[z] * xvb[k * 3 + c];
      }
      *(f16x8*)&SP[off] = outv;
    }
  };

  f32x4 accqA[4][2], accqB[4][2];
  f32x4 P1[4][2], P4[4][2], P2[4][2], P3[4][2];

  // q1 (w1): A1 = w1 (x) xs ; P1 = A1 @ WL0a. Queue q4 gemm before barrier.
  qgemm(0, accqA);
  sw_write(accqA);
  tp_xs();
  qgemm(384, accqB);          // w4, independent — fills the barrier wait
  __syncthreads();            // B1: SP(A1) complete
  fold(WL0h, 0, P1);
  sw_write(accqB);            // SW <- w4 (SW(w1) readers all pre-B1)
  load_xv();
  __syncthreads();            // B2: all folds done reading SP(A1)
  tp_w4();
  qgemm(128, accqA);          // w2 queued
  __syncthreads();            // B3: SP(A4) complete
  fold(WL0h, 1, P4);
  sw_write(accqA);            // SW <- w2 (tp_w4 reads all pre-B3)

  // scalar part: MIDs[:, j] = y0*P1 + P4/sqrt(3). Row = sender-sorted pos.
#pragma unroll
  for (int rt = 0; rt < 4; ++rt)
#pragma unroll
    for (int r4 = 0; r4 < 4; ++r4) {
      int row = rt * 16 + g * 4 + r4;
      int elw = SIDX[e0 + row];
      float4 ea = *(const float4*)&edge_attrs[(size_t)elw * 4];
      f16x2 pk;
      pk[0] = (_Float16)(ea.x * P1[rt][0][r4] + INV_SQRT3F * P4[rt][0][r4]);
      pk[1] = (_Float16)(ea.x * P1[rt][1][r4] + INV_SQRT3F * P4[rt][1][r4]);
      *(f16x2*)&MIDs[(size_t)(e0 + row) * 512 + wv * 32 + m * 2] = pk;
    }
  __syncthreads();            // B4: folds done reading SP(A4)
  tp_xs();                    // SP <- A2 (reads SW(w2), own wave, pre-B4)
  qgemm(256, accqB);          // w3 queued
  __syncthreads();            // B5: SP(A2) complete
  fold(WL1h, 0, P2);
  sw_write(accqB);            // SW <- w3 (tp_xs reads all pre-B5)
  __syncthreads();            // B6: folds done reading SP(A2)

#pragma unroll
  for (int c = 0; c < 3; ++c) {
    tp_w3(c);                 // SP <- A3c (reads SW(w3), own wave)
    __syncthreads();          // SP complete
    fold(WL1h, 1, P3);
    // plane c: MIDs[:, 128 + c*128 + j] = yv[c]*P2 + y0*P3
#pragma unroll
    for (int rt = 0; rt < 4; ++rt)
#pragma unroll
      for (int r4 = 0; r4 < 4; ++r4) {
        int row = rt * 16 + g * 4 + r4;
        int elw = SIDX[e0 + row];
        float4 ea = *(const float4*)&edge_attrs[(size_t)elw * 4];
        float yvc = (c == 0) ? ea.y : (c == 1) ? ea.z : ea.w;
        f16x2 pk;
        pk[0] = (_Float16)(yvc * P2[rt][0][r4] + ea.x * P3[rt][0][r4]);
        pk[1] = (_Float16)(yvc * P2[rt][1][r4] + ea.x * P3[rt][1][r4]);
        *(f16x2*)&MIDs[(size_t)(e0 + row) * 512 + 128 + c * 128 + wv * 32 + m * 2] = pk;
      }
    if (c < 2) __syncthreads();  // folds done reading SP before next tp_w3
  }
}

// ---------------------------------------------------------------------------
// Gather: one block per node; LDS-staged edge ids + 4-way unroll; output row
// staged in LDS and stored coalesced (float2/lane). EIDX holds sender-sorted
// positions => MIDs rows are contiguous per edge_mlp block.
// ---------------------------------------------------------------------------
__global__ __launch_bounds__(256) void gather_msg(
    const _Float16* __restrict__ MIDs, const int* __restrict__ OFF,
    const int* __restrict__ EIDX, float* __restrict__ out) {
  __shared__ int eb[256];
  __shared__ float os[512];
  const int n = blockIdx.x;
  const int t = threadIdx.x;
  const int beg = OFF[n], end = OFF[n + 1];
  float a0 = 0.f, a1 = 0.f;
  for (int base = beg; base < end; base += 256) {
    int cnt = min(256, end - base);
    __syncthreads();
    if (t < cnt) eb[t] = EIDX[base + t];
    __syncthreads();
    int k = 0;
    for (; k + 4 <= cnt; k += 4) {
      int e0_ = eb[k], e1_ = eb[k + 1], e2_ = eb[k + 2], e3_ = eb[k + 3];
      f16x2 v0 = *(const f16x2*)&MIDs[(size_t)e0_ * 512 + t * 2];
      f16x2 v1 = *(const f16x2*)&MIDs[(size_t)e1_ * 512 + t * 2];
      f16x2 v2 = *(const f16x2*)&MIDs[(size_t)e2_ * 512 + t * 2];
      f16x2 v3 = *(const f16x2*)&MIDs[(size_t)e3_ * 512 + t * 2];
      a0 += (float)v0[0] + (float)v1[0] + (float)v2[0] + (float)v3[0];
      a1 += (float)v0[1] + (float)v1[1] + (float)v2[1] + (float)v3[1];
    }
    for (; k < cnt; ++k) {
      f16x2 v = *(const f16x2*)&MIDs[(size_t)eb[k] * 512 + t * 2];
      a0 += (float)v[0];
      a1 += (float)v[1];
    }
  }
#pragma unroll
  for (int u = 0; u < 2; ++u) {
    int x = t * 2 + u;
    float a = u ? a1 : a0;
    int dst;
    if (x < 128) {
      dst = x * 4;
    } else {
      int xm = x - 128;
      int c = xm >> 7, j = xm & 127;
      dst = j * 4 + 1 + c;
    }
    os[dst] = a;
  }
  __syncthreads();
  *(float2*)&out[(size_t)n * 512 + t * 2] = *(const float2*)&os[t * 2];
}

// ---------------------------------------------------------------------------
extern "C" void kernel_launch(void* const* d_in, const int* in_sizes, int n_in,
                              void* d_out, int out_size, void* d_ws, size_t ws_size,
                              hipStream_t stream) {
  const float* node_feats = (const float*)d_in[1];
  const float* edge_attrs = (const float*)d_in[2];
  const float* edge_feats = (const float*)d_in[3];
  const int*   edge_index = (const int*)d_in[4];
  const float* W_up0   = (const float*)d_in[5];
  const float* W_up1   = (const float*)d_in[6];
  const float* W_down  = (const float*)d_in[7];
  const float* Wm0     = (const float*)d_in[8];
  const float* Wm1     = (const float*)d_in[9];
  const float* Wm2     = (const float*)d_in[10];
  const float* Wm3     = (const float*)d_in[11];
  const float* W_lin0  = (const float*)d_in[12];
  const float* W_lin1  = (const float*)d_in[13];
  const float* W_skip0 = (const float*)d_in[14];
  const float* W_skip1 = (const float*)d_in[15];
  float* out = (float*)d_out;

  char* ws = (char*)d_ws;
  size_t off = 0;
  auto alloc = [&](size_t bytes) {
    void* p = ws + off;
    off = (off + bytes + 255) & ~(size_t)255;
    return p;
  };
  _Float16* UPH   = (_Float16*)alloc((size_t)NN * 512 * 2);
  _Float16* DOWNH = (_Float16*)alloc((size_t)NN * 64 * 2);
  _Float16* W0h   = (_Float16*)alloc(160 * 256 * 2);
  _Float16* W1h   = (_Float16*)alloc(256 * 256 * 2);
  _Float16* W2h   = (_Float16*)alloc(256 * 256 * 2);
  _Float16* W3h   = (_Float16*)alloc(256 * 512 * 2);
  _Float16* WL0h  = (_Float16*)alloc(256 * 128 * 2);
  _Float16* WL1h  = (_Float16*)alloc(256 * 128 * 2);
  int*      CNT   = (int*)alloc((size_t)NN * 4);
  int*      CNT2  = (int*)alloc((size_t)NN * 4);
  int*      OFF   = (int*)alloc((size_t)(NN + 1) * 4);
  int*      CUR   = (int*)alloc((size_t)NN * 4);
  int*      EIDX  = (int*)alloc((size_t)NE * 4);
  int*      OFF2  = (int*)alloc((size_t)(NN + 1) * 4);
  int*      CUR2  = (int*)alloc((size_t)NN * 4);
  int*      SIDX  = (int*)alloc((size_t)NE * 4);
  _Float16* MIDs  = (_Float16*)alloc((size_t)NE * 512 * 2);

  // scales folded into fp16 weights: 1/sqrt(136) layer0, 1/16 layers 1..3,
  // 1/256 for W_lin (includes sqrt(2C) and AVG_NEIGH)
  prep<<<2018, 256, 0, stream>>>(Wm0, Wm1, Wm2, Wm3, W_lin0, W_lin1,
                                 W0h, W1h, W2h, W3h, WL0h, WL1h,
                                 node_feats, W_up0, W_skip0, W_down,
                                 W_up1, W_skip1,
                                 UPH, DOWNH, out + (size_t)NN * 512);

  // cooperative CSR: zero -> count -> scan -> fill in one launch
  {
    const int* ei = edge_index;
    void* args[] = {(void*)&ei, (void*)&CNT, (void*)&CNT2,
                    (void*)&OFF, (void*)&CUR, (void*)&OFF2, (void*)&CUR2,
                    (void*)&EIDX, (void*)&SIDX};
    hipLaunchCooperativeKernel((const void*)k_csr, dim3(256), dim3(256),
                               args, 0, stream);
  }

  edge_mlp<<<2500, 256, 0, stream>>>(edge_attrs, edge_feats, edge_index, SIDX,
                                     DOWNH, UPH, W0h, W1h, W2h, W3h, WL0h, WL1h,
                                     MIDs);
  gather_msg<<<NN, 256, 0, stream>>>(MIDs, OFF, EIDX, out);
}

// Round 6
// 461.457 us; speedup vs baseline: 1.2876x; 1.2876x over previous
//
#include <hip/hip_runtime.h>
#include <cmath>

#define NN 10000
#define NE 160000
#define INV_SQRT_C 0.08838834764831845f   // 1/sqrt(128)
#define INV_SQRT3F 0.5773502691896258f

typedef _Float16 f16x8 __attribute__((ext_vector_type(8)));
typedef _Float16 f16x4 __attribute__((ext_vector_type(4)));
typedef _Float16 f16x2 __attribute__((ext_vector_type(2)));
typedef float    f32x4 __attribute__((ext_vector_type(4)));

__device__ __forceinline__ float silu_f(float x) {
  return x / (1.f + __expf(-x));
}

// ---------------------------------------------------------------------------
// prep superkernel (regular launch, NOT cooperative — round-5's coop CSR
// serialized the pipeline at +120 us):
//   blocks [0,768):     weight conversion (6 jobs x 128 blocks)
//   blocks [768,2018):  node pre-pass (625 s-blocks + 625 v-blocks)
//   blocks [2018,2643): edge-endpoint counting (independent of the above;
//                       its scattered atomics hide under node_pre compute)
// CNT/CNT2 zeroed by the preceding memset dispatch.
// ---------------------------------------------------------------------------
__device__ __forceinline__ void wconv_one(
    int bx, const float* __restrict__ src, _Float16* __restrict__ dst,
    int Korig, int Kpad, int N, float scale, int P) {
  int total = Kpad * N;
  for (int t = bx * 256 + threadIdx.x; t < total; t += 128 * 256) {
    int n = t % N;
    int k = t / N;
    int kb = k >> 5, kk = k & 31;
    int sub = n & (P - 1);
    int n_l = (n & ~(P - 1)) | ((sub & 15) * (P >> 4) + (sub >> 4));
    float v = (k < Korig) ? src[(size_t)k * N + n_l] * scale : 0.f;
    dst[((size_t)(kb * N + n) << 5) + kk] = (_Float16)v;
  }
}

__global__ __launch_bounds__(256) void prep(
    const float* __restrict__ s0, const float* __restrict__ s1,
    const float* __restrict__ s2, const float* __restrict__ s3,
    const float* __restrict__ s4, const float* __restrict__ s5,
    _Float16* __restrict__ d0, _Float16* __restrict__ d1,
    _Float16* __restrict__ d2, _Float16* __restrict__ d3,
    _Float16* __restrict__ d4, _Float16* __restrict__ d5,
    const float* __restrict__ feats,
    const float* __restrict__ W_up0, const float* __restrict__ W_skip0,
    const float* __restrict__ W_down,
    const float* __restrict__ W_up1, const float* __restrict__ W_skip1,
    _Float16* __restrict__ UPH, _Float16* __restrict__ DOWNH,
    float* __restrict__ out_sc,
    const int* __restrict__ edge_index,
    int* __restrict__ CNT, int* __restrict__ CNT2) {
  __shared__ float ls[16 * 512];   // 32 KB: s-pass uses [16][128]; v-pass
                                   // uses as float4 [16][128] (c0,c1,c2,pad)
  const int b = blockIdx.x;
  const int t = threadIdx.x;

  if (b < 768) {
    const int job = b >> 7, bx = b & 127;
    switch (job) {
      case 0: wconv_one(bx, s0, d0, 136, 160, 256, 0.08574929257125442f, 64); break;
      case 1: wconv_one(bx, s1, d1, 256, 256, 256, 0.0625f, 64); break;
      case 2: wconv_one(bx, s2, d2, 256, 256, 256, 0.0625f, 64); break;
      case 3: wconv_one(bx, s3, d3, 256, 256, 512, 0.0625f, 32); break;
      case 4: wconv_one(bx, s4, d4, 256, 256, 128, 1.0f / 256.0f, 32); break;
      default: wconv_one(bx, s5, d5, 256, 256, 128, 1.0f / 256.0f, 32); break;
    }
    return;
  }
  if (b >= 2018) {
    // edge-endpoint counting (exactly 625*256 = NE threads)
    int e = (b - 2018) * 256 + t;
    if (e < NE) {
      int2 sr = *(const int2*)&edge_index[(size_t)e * 2];
      atomicAdd(&CNT[sr.y], 1);    // receiver
      atomicAdd(&CNT2[sr.x], 1);   // sender
    }
    return;
  }

  const int nb = b - 768;
  if (nb < 625) {
    const int n0 = nb * 16;
    for (int f = t; f < 16 * 128; f += 256) {
      int r = f >> 7, c = f & 127;
      ls[r * 128 + c] = feats[(size_t)(n0 + r) * 512 + c];
    }
    __syncthreads();
    {
      int j = t & 127, g = t >> 7;  // 8 nodes per group
      float au[8] = {0, 0, 0, 0, 0, 0, 0, 0};
      float ak[8] = {0, 0, 0, 0, 0, 0, 0, 0};
      for (int i = 0; i < 128; ++i) {
        float wu = W_up0[(size_t)i * 128 + j];
        float wk = W_skip0[(size_t)i * 128 + j];
#pragma unroll
        for (int r = 0; r < 8; ++r) {
          float s = ls[(g * 8 + r) * 128 + i];
          au[r] += s * wu;
          ak[r] += s * wk;
        }
      }
#pragma unroll
      for (int r = 0; r < 8; ++r) {
        int n = n0 + g * 8 + r;
        UPH[(size_t)n * 512 + j] = (_Float16)(au[r] * INV_SQRT_C);
        out_sc[(size_t)n * 512 + j] = ak[r] * INV_SQRT_C;
      }
    }
    {
      int j = t & 63, g = t >> 6;  // 4 nodes per group
      float ad[4] = {0, 0, 0, 0};
      for (int i = 0; i < 128; ++i) {
        float wd = W_down[(size_t)i * 64 + j];
#pragma unroll
        for (int r = 0; r < 4; ++r) ad[r] += ls[(g * 4 + r) * 128 + i] * wd;
      }
#pragma unroll
      for (int r = 0; r < 4; ++r)
        DOWNH[(size_t)(n0 + g * 4 + r) * 64 + j] = (_Float16)(ad[r] * INV_SQRT_C);
    }
  } else {
    const int n0 = (nb - 625) * 16;
    // stage v-tile as float4 slots {c0,c1,c2,pad}: inner loop reads ONE
    // ds_read_b128 per (node,i) instead of 3 scalar ds_read_b32 (the v-pass
    // was LDS-instruction-bound: 24 scalar reads per K-iter per thread).
    for (int f = t; f < 16 * 384; f += 256) {
      int r = f / 384, c = f % 384;
      int i = c / 3, cc = c - i * 3;
      ls[(r * 128 + i) * 4 + cc] = feats[(size_t)(n0 + r) * 512 + 128 + c];
    }
    __syncthreads();
    const float4* lv = (const float4*)ls;
    int j = t & 127, g = t >> 7;
    float au[8][3], ak[8][3];
#pragma unroll
    for (int r = 0; r < 8; ++r)
#pragma unroll
      for (int c = 0; c < 3; ++c) { au[r][c] = 0.f; ak[r][c] = 0.f; }
    for (int i = 0; i < 128; ++i) {
      float wu = W_up1[(size_t)i * 128 + j];
      float wk = W_skip1[(size_t)i * 128 + j];
#pragma unroll
      for (int r = 0; r < 8; ++r) {
        float4 v = lv[(g * 8 + r) * 128 + i];
        au[r][0] += v.x * wu; au[r][1] += v.y * wu; au[r][2] += v.z * wu;
        ak[r][0] += v.x * wk; ak[r][1] += v.y * wk; ak[r][2] += v.z * wk;
      }
    }
#pragma unroll
    for (int r = 0; r < 8; ++r) {
      int n = n0 + g * 8 + r;
#pragma unroll
      for (int c = 0; c < 3; ++c) {
        UPH[(size_t)n * 512 + 128 + j * 3 + c] = (_Float16)(au[r][c] * INV_SQRT_C);
        out_sc[(size_t)n * 512 + 128 + j * 3 + c] = ak[r][c] * INV_SQRT_C;
      }
    }
  }
}

// ---------------------------------------------------------------------------
// CSR scan + fill (verbatim round 4): scan launch grid=2 (both scans in
// parallel), fill writes EIDX = sender-sorted position for gather.
// ---------------------------------------------------------------------------
__device__ __forceinline__ void scan_one(const int* __restrict__ CNT,
                                         int* __restrict__ OFF,
                                         int* __restrict__ CUR, int* ts) {
  const int t = threadIdx.x;
  const int base = t * 10;
  int loc[10];
  int s = 0;
#pragma unroll
  for (int i = 0; i < 10; ++i) {
    int idx = base + i;
    int v = (idx < NN) ? CNT[idx] : 0;
    loc[i] = s;
    s += v;
  }
  ts[t] = s;
  __syncthreads();
  for (int off = 1; off < 1024; off <<= 1) {
    int v = (t >= off) ? ts[t - off] : 0;
    __syncthreads();
    ts[t] += v;
    __syncthreads();
  }
  int tp = (t > 0) ? ts[t - 1] : 0;
#pragma unroll
  for (int i = 0; i < 10; ++i) {
    int idx = base + i;
    if (idx < NN) {
      OFF[idx] = tp + loc[i];
      CUR[idx] = tp + loc[i];
    }
  }
  if (t == 1023) OFF[NN] = ts[1023];
}

__global__ __launch_bounds__(1024) void k_scan2(
    const int* __restrict__ CNT, int* __restrict__ OFF, int* __restrict__ CUR,
    const int* __restrict__ CNT2, int* __restrict__ OFF2, int* __restrict__ CUR2) {
  __shared__ int ts[1024];
  if (blockIdx.x == 0) scan_one(CNT, OFF, CUR, ts);
  else                 scan_one(CNT2, OFF2, CUR2, ts);
}

__global__ void k_fill2(const int* __restrict__ edge_index,
                        int* __restrict__ CUR, int* __restrict__ EIDX,
                        int* __restrict__ CUR2, int* __restrict__ SIDX) {
  int e = blockIdx.x * blockDim.x + threadIdx.x;
  if (e < NE) {
    int2 sr = *(const int2*)&edge_index[(size_t)e * 2];
    int ps = atomicAdd(&CUR2[sr.x], 1);  // sender-sorted position
    SIDX[ps] = e;
    int pr = atomicAdd(&CUR[sr.y], 1);   // receiver-CSR slot
    EIDX[pr] = ps;                       // gather reads MIDs[ps]
  }
}

// ---------------------------------------------------------------------------
// Fused edge kernel — round-0 verified structure (HA/HB ping-pong, SW/SP
// separate, original barrier schedule; 64 KB LDS, 2 blocks/CU, 128 VGPR).
// MIDs rows indexed by sender-sorted position (e0 + row) => contiguous per
// block. VERBATIM from round 4 (257.6 us, absmax 0.002).
// ---------------------------------------------------------------------------
__device__ __forceinline__ void mlp_layer_256(
    const _Float16* In, _Float16* Out, const _Float16* __restrict__ Wz,
    int m, int g, int wv) {
  f32x4 acc[4][4];
  f32x4 zero4 = {0.f, 0.f, 0.f, 0.f};
#pragma unroll
  for (int rt = 0; rt < 4; ++rt)
#pragma unroll
    for (int ct = 0; ct < 4; ++ct) acc[rt][ct] = zero4;

#pragma unroll
  for (int kb = 0; kb < 8; ++kb) {
    f16x8 a[4], b[4];
#pragma unroll
    for (int rt = 0; rt < 4; ++rt) {
      int row = rt * 16 + m;
      a[rt] = *(const f16x8*)&In[row * 256 + (((kb * 2 + (g >> 1)) ^ m) << 4) + (g & 1) * 8];
    }
#pragma unroll
    for (int ct = 0; ct < 4; ++ct)
      b[ct] = *(const f16x8*)&Wz[((size_t)(kb * 256 + wv * 64 + ct * 16 + m) << 5) + g * 8];
#pragma unroll
    for (int rt = 0; rt < 4; ++rt)
#pragma unroll
      for (int ct = 0; ct < 4; ++ct)
        acc[rt][ct] = __builtin_amdgcn_mfma_f32_16x16x32_f16(a[rt], b[ct], acc[rt][ct], 0, 0, 0);
  }
#pragma unroll
  for (int rt = 0; rt < 4; ++rt)
#pragma unroll
    for (int q = 0; q < 4; ++q) {
      int row = rt * 16 + g * 4 + q;
      f16x4 pk;
#pragma unroll
      for (int ct = 0; ct < 4; ++ct) pk[ct] = (_Float16)silu_f(acc[rt][ct][q]);
      int blk = (wv * 4 + (m >> 2)) ^ (row & 15);
      *(f16x4*)&Out[row * 256 + (blk << 4) + (m & 3) * 4] = pk;
    }
}

__global__ __launch_bounds__(256, 2) void edge_mlp(
    const float* __restrict__ edge_attrs,
    const float* __restrict__ edge_feats,
    const int* __restrict__ edge_index,
    const int* __restrict__ SIDX,
    const _Float16* __restrict__ DOWNH,
    const _Float16* __restrict__ UPH,
    const _Float16* __restrict__ W0h, const _Float16* __restrict__ W1h,
    const _Float16* __restrict__ W2h, const _Float16* __restrict__ W3h,
    const _Float16* __restrict__ WL0h, const _Float16* __restrict__ WL1h,
    _Float16* __restrict__ MIDs) {
  __shared__ _Float16 HA[64 * 256];
  __shared__ _Float16 HB[64 * 256];

  const int tid = threadIdx.x;
  const int lane = tid & 63;
  const int wv = tid >> 6;
  const int m = lane & 15;
  const int g = lane >> 4;
  const int e0 = blockIdx.x * 64;
  const int nw = wv * 64;

  int el_r[4], snd_r[4], rcv_r[4];
#pragma unroll
  for (int rt = 0; rt < 4; ++rt) {
    el_r[rt] = SIDX[e0 + rt * 16 + m];
    int2 sr = *(const int2*)&edge_index[(size_t)el_r[rt] * 2];
    snd_r[rt] = sr.x;
    rcv_r[rt] = sr.y;
  }

  f32x4 zero4 = {0.f, 0.f, 0.f, 0.f};
  f16x8 zf = {0, 0, 0, 0, 0, 0, 0, 0};

  // ---------------- layer 0: aug(136, padded 160) -> h1 (HA)
  {
    f32x4 acc[4][4];
#pragma unroll
    for (int rt = 0; rt < 4; ++rt)
#pragma unroll
      for (int ct = 0; ct < 4; ++ct) acc[rt][ct] = zero4;

#pragma unroll
    for (int kb = 0; kb < 5; ++kb) {
      const int k0 = kb * 32 + g * 8;
      f16x8 a[4], b[4];
#pragma unroll
      for (int rt = 0; rt < 4; ++rt) {
        if (k0 == 0) {
          const float* ef = &edge_feats[(size_t)el_r[rt] * 8];
          float4 f0 = *(const float4*)ef;
          float4 f1 = *(const float4*)(ef + 4);
          f16x8 av;
          av[0] = (_Float16)f0.x; av[1] = (_Float16)f0.y;
          av[2] = (_Float16)f0.z; av[3] = (_Float16)f0.w;
          av[4] = (_Float16)f1.x; av[5] = (_Float16)f1.y;
          av[6] = (_Float16)f1.z; av[7] = (_Float16)f1.w;
          a[rt] = av;
        } else if (k0 < 72) {
          a[rt] = *(const f16x8*)&DOWNH[(size_t)snd_r[rt] * 64 + (k0 - 8)];
        } else if (k0 < 136) {
          a[rt] = *(const f16x8*)&DOWNH[(size_t)rcv_r[rt] * 64 + (k0 - 72)];
        } else {
          a[rt] = zf;
        }
      }
#pragma unroll
      for (int ct = 0; ct < 4; ++ct)
        b[ct] = *(const f16x8*)&W0h[((size_t)(kb * 256 + nw + ct * 16 + m) << 5) + g * 8];
#pragma unroll
      for (int rt = 0; rt < 4; ++rt)
#pragma unroll
        for (int ct = 0; ct < 4; ++ct)
          acc[rt][ct] = __builtin_amdgcn_mfma_f32_16x16x32_f16(a[rt], b[ct], acc[rt][ct], 0, 0, 0);
    }
#pragma unroll
    for (int rt = 0; rt < 4; ++rt)
#pragma unroll
      for (int q = 0; q < 4; ++q) {
        int row = rt * 16 + g * 4 + q;
        f16x4 pk;
#pragma unroll
        for (int ct = 0; ct < 4; ++ct) pk[ct] = (_Float16)silu_f(acc[rt][ct][q]);
        int blk = (wv * 4 + (m >> 2)) ^ (row & 15);
        *(f16x4*)&HA[row * 256 + (blk << 4) + (m & 3) * 4] = pk;
      }
  }
  __syncthreads();

  mlp_layer_256(HA, HB, W1h, m, g, wv);   // layer 1: h1 -> h2
  __syncthreads();
  mlp_layer_256(HB, HA, W2h, m, g, wv);   // layer 2: h2 -> h3 (HA stays live)
  __syncthreads();

  // ================= epilogue =================
  _Float16* SW = HB;             // 64 x 128 fp16, tpw quarter
  _Float16* SP = HB + 64 * 128;  // 64 x 128 fp16, TP'd A-matrix

  const int e_loc = lane;
  const int ers = (e_loc ^ (e_loc >> 3)) & 7;
  const int elc = SIDX[e0 + e_loc];
  const int snd_e = edge_index[(size_t)elc * 2];
  const _Float16* uprow = &UPH[(size_t)snd_e * 512];

  // quarter GEMM into caller-provided acc buffer
  auto qgemm = [&](int qbase, f32x4 (&accq)[4][2]) {
#pragma unroll
    for (int rt = 0; rt < 4; ++rt)
#pragma unroll
      for (int ct = 0; ct < 2; ++ct) accq[rt][ct] = zero4;
#pragma unroll
    for (int kb = 0; kb < 8; ++kb) {
      f16x8 a[4], b[2];
#pragma unroll
      for (int rt = 0; rt < 4; ++rt) {
        int row = rt * 16 + m;
        a[rt] = *(const f16x8*)&HA[row * 256 + (((kb * 2 + (g >> 1)) ^ m) << 4) + (g & 1) * 8];
      }
#pragma unroll
      for (int ct = 0; ct < 2; ++ct)
        b[ct] = *(const f16x8*)&W3h[((size_t)(kb * 512 + qbase + wv * 32 + ct * 16 + m) << 5) + g * 8];
#pragma unroll
      for (int rt = 0; rt < 4; ++rt)
#pragma unroll
        for (int ct = 0; ct < 2; ++ct)
          accq[rt][ct] = __builtin_amdgcn_mfma_f32_16x16x32_f16(a[rt], b[ct], accq[rt][ct], 0, 0, 0);
    }
  };

  auto sw_write = [&](const f32x4 (&accq)[4][2]) {
#pragma unroll
    for (int rt = 0; rt < 4; ++rt)
#pragma unroll
      for (int r4 = 0; r4 < 4; ++r4) {
        int row = rt * 16 + g * 4 + r4;
        int rs = (row ^ (row >> 3)) & 7;
        f16x2 pk;
        pk[0] = (_Float16)accq[rt][0][r4];
        pk[1] = (_Float16)accq[rt][1][r4];
        int blk = ((wv * 2 + (m >> 3)) ^ rs) & 7;
        *(f16x2*)&SW[row * 128 + (blk << 4) + (m & 7) * 2] = pk;
      }
  };

  auto fold = [&](const _Float16* __restrict__ WLh, int qpart, f32x4 (&P)[4][2]) {
#pragma unroll
    for (int rt = 0; rt < 4; ++rt)
#pragma unroll
      for (int ct = 0; ct < 2; ++ct) P[rt][ct] = zero4;
#pragma unroll
    for (int kb = 0; kb < 4; ++kb) {
      f16x8 a[4], b[2];
#pragma unroll
      for (int rt = 0; rt < 4; ++rt) {
        int row = rt * 16 + m;
        int rs = (row ^ (row >> 3)) & 7;
        a[rt] = *(const f16x8*)&SP[row * 128 + ((((kb * 2 + (g >> 1)) ^ rs) & 7) << 4) + (g & 1) * 8];
      }
#pragma unroll
      for (int ct = 0; ct < 2; ++ct)
        b[ct] = *(const f16x8*)&WLh[((size_t)((qpart * 4 + kb) * 128 + wv * 32 + ct * 16 + m) << 5) + g * 8];
#pragma unroll
      for (int rt = 0; rt < 4; ++rt)
#pragma unroll
        for (int ct = 0; ct < 2; ++ct)
          P[rt][ct] = __builtin_amdgcn_mfma_f32_16x16x32_f16(a[rt], b[ct], P[rt][ct], 0, 0, 0);
    }
  };

  auto tp_xs = [&]() {
#pragma unroll
    for (int cch = 0; cch < 4; ++cch) {
      int ib = nw / 2 + cch * 8;
      int blk = ((ib >> 4) ^ ers) & 7;
      int off = e_loc * 128 + (blk << 4) + (ib & 15);
      f16x8 swv = *(const f16x8*)&SW[off];
      f16x8 upv = *(const f16x8*)&uprow[ib];
      f16x8 pr = swv * upv;
      *(f16x8*)&SP[off] = pr;
    }
  };

  _Float16 xvb[96];
  auto load_xv = [&]() {
#pragma unroll
    for (int u = 0; u < 12; ++u) {
      f16x8 t = *(const f16x8*)&uprow[128 + wv * 96 + u * 8];
#pragma unroll
      for (int z = 0; z < 8; ++z) xvb[u * 8 + z] = t[z];
    }
  };

  auto tp_w4 = [&]() {
    float4 ea = *(const float4*)&edge_attrs[(size_t)elc * 4];
#pragma unroll
    for (int cch = 0; cch < 4; ++cch) {
      int ib = nw / 2 + cch * 8;
      int blk = ((ib >> 4) ^ ers) & 7;
      int off = e_loc * 128 + (blk << 4) + (ib & 15);
      f16x8 swv = *(const f16x8*)&SW[off];
      f16x8 outv;
#pragma unroll
      for (int z = 0; z < 8; ++z) {
        int k = cch * 8 + z;
        float d = (float)xvb[k * 3] * ea.y + (float)xvb[k * 3 + 1] * ea.z +
                  (float)xvb[k * 3 + 2] * ea.w;
        outv[z] = (_Float16)((float)swv[z] * d);
      }
      *(f16x8*)&SP[off] = outv;
    }
  };

  auto tp_w3 = [&](int c) {
#pragma unroll
    for (int cch = 0; cch < 4; ++cch) {
      int ib = nw / 2 + cch * 8;
      int blk = ((ib >> 4) ^ ers) & 7;
      int off = e_loc * 128 + (blk << 4) + (ib & 15);
      f16x8 swv = *(const f16x8*)&SW[off];
      f16x8 outv;
#pragma unroll
      for (int z = 0; z < 8; ++z) {
        int k = cch * 8 + z;
        outv[z] = swv[z] * xvb[k * 3 + c];
      }
      *(f16x8*)&SP[off] = outv;
    }
  };

  f32x4 accqA[4][2], accqB[4][2];
  f32x4 P1[4][2], P4[4][2], P2[4][2], P3[4][2];

  // q1 (w1): A1 = w1 (x) xs ; P1 = A1 @ WL0a. Queue q4 gemm before barrier.
  qgemm(0, accqA);
  sw_write(accqA);
  tp_xs();
  qgemm(384, accqB);          // w4, independent — fills the barrier wait
  __syncthreads();            // B1: SP(A1) complete
  fold(WL0h, 0, P1);
  sw_write(accqB);            // SW <- w4 (SW(w1) readers all pre-B1)
  load_xv();
  __syncthreads();            // B2: all folds done reading SP(A1)
  tp_w4();
  qgemm(128, accqA);          // w2 queued
  __syncthreads();            // B3: SP(A4) complete
  fold(WL0h, 1, P4);
  sw_write(accqA);            // SW <- w2 (tp_w4 reads all pre-B3)

  // scalar part: MIDs[:, j] = y0*P1 + P4/sqrt(3). Row = sender-sorted pos.
#pragma unroll
  for (int rt = 0; rt < 4; ++rt)
#pragma unroll
    for (int r4 = 0; r4 < 4; ++r4) {
      int row = rt * 16 + g * 4 + r4;
      int elw = SIDX[e0 + row];
      float4 ea = *(const float4*)&edge_attrs[(size_t)elw * 4];
      f16x2 pk;
      pk[0] = (_Float16)(ea.x * P1[rt][0][r4] + INV_SQRT3F * P4[rt][0][r4]);
      pk[1] = (_Float16)(ea.x * P1[rt][1][r4] + INV_SQRT3F * P4[rt][1][r4]);
      *(f16x2*)&MIDs[(size_t)(e0 + row) * 512 + wv * 32 + m * 2] = pk;
    }
  __syncthreads();            // B4: folds done reading SP(A4)
  tp_xs();                    // SP <- A2 (reads SW(w2), own wave, pre-B4)
  qgemm(256, accqB);          // w3 queued
  __syncthreads();            // B5: SP(A2) complete
  fold(WL1h, 0, P2);
  sw_write(accqB);            // SW <- w3 (tp_xs reads all pre-B5)
  __syncthreads();            // B6: folds done reading SP(A2)

#pragma unroll
  for (int c = 0; c < 3; ++c) {
    tp_w3(c);                 // SP <- A3c (reads SW(w3), own wave)
    __syncthreads();          // SP complete
    fold(WL1h, 1, P3);
    // plane c: MIDs[:, 128 + c*128 + j] = yv[c]*P2 + y0*P3
#pragma unroll
    for (int rt = 0; rt < 4; ++rt)
#pragma unroll
      for (int r4 = 0; r4 < 4; ++r4) {
        int row = rt * 16 + g * 4 + r4;
        int elw = SIDX[e0 + row];
        float4 ea = *(const float4*)&edge_attrs[(size_t)elw * 4];
        float yvc = (c == 0) ? ea.y : (c == 1) ? ea.z : ea.w;
        f16x2 pk;
        pk[0] = (_Float16)(yvc * P2[rt][0][r4] + ea.x * P3[rt][0][r4]);
        pk[1] = (_Float16)(yvc * P2[rt][1][r4] + ea.x * P3[rt][1][r4]);
        *(f16x2*)&MIDs[(size_t)(e0 + row) * 512 + 128 + c * 128 + wv * 32 + m * 2] = pk;
      }
    if (c < 2) __syncthreads();  // folds done reading SP before next tp_w3
  }
}

// ---------------------------------------------------------------------------
// Gather: one block per node; LDS-staged edge ids + 4-way unroll; output row
// staged in LDS and stored coalesced (float2/lane). EIDX holds sender-sorted
// positions => MIDs rows are contiguous per edge_mlp block.
// ---------------------------------------------------------------------------
__global__ __launch_bounds__(256) void gather_msg(
    const _Float16* __restrict__ MIDs, const int* __restrict__ OFF,
    const int* __restrict__ EIDX, float* __restrict__ out) {
  __shared__ int eb[256];
  __shared__ float os[512];
  const int n = blockIdx.x;
  const int t = threadIdx.x;
  const int beg = OFF[n], end = OFF[n + 1];
  float a0 = 0.f, a1 = 0.f;
  for (int base = beg; base < end; base += 256) {
    int cnt = min(256, end - base);
    __syncthreads();
    if (t < cnt) eb[t] = EIDX[base + t];
    __syncthreads();
    int k = 0;
    for (; k + 4 <= cnt; k += 4) {
      int e0_ = eb[k], e1_ = eb[k + 1], e2_ = eb[k + 2], e3_ = eb[k + 3];
      f16x2 v0 = *(const f16x2*)&MIDs[(size_t)e0_ * 512 + t * 2];
      f16x2 v1 = *(const f16x2*)&MIDs[(size_t)e1_ * 512 + t * 2];
      f16x2 v2 = *(const f16x2*)&MIDs[(size_t)e2_ * 512 + t * 2];
      f16x2 v3 = *(const f16x2*)&MIDs[(size_t)e3_ * 512 + t * 2];
      a0 += (float)v0[0] + (float)v1[0] + (float)v2[0] + (float)v3[0];
      a1 += (float)v0[1] + (float)v1[1] + (float)v2[1] + (float)v3[1];
    }
    for (; k < cnt; ++k) {
      f16x2 v = *(const f16x2*)&MIDs[(size_t)eb[k] * 512 + t * 2];
      a0 += (float)v[0];
      a1 += (float)v[1];
    }
  }
#pragma unroll
  for (int u = 0; u < 2; ++u) {
    int x = t * 2 + u;
    float a = u ? a1 : a0;
    int dst;
    if (x < 128) {
      dst = x * 4;
    } else {
      int xm = x - 128;
      int c = xm >> 7, j = xm & 127;
      dst = j * 4 + 1 + c;
    }
    os[dst] = a;
  }
  __syncthreads();
  *(float2*)&out[(size_t)n * 512 + t * 2] = *(const float2*)&os[t * 2];
}

// ---------------------------------------------------------------------------
extern "C" void kernel_launch(void* const* d_in, const int* in_sizes, int n_in,
                              void* d_out, int out_size, void* d_ws, size_t ws_size,
                              hipStream_t stream) {
  const float* node_feats = (const float*)d_in[1];
  const float* edge_attrs = (const float*)d_in[2];
  const float* edge_feats = (const float*)d_in[3];
  const int*   edge_index = (const int*)d_in[4];
  const float* W_up0   = (const float*)d_in[5];
  const float* W_up1   = (const float*)d_in[6];
  const float* W_down  = (const float*)d_in[7];
  const float* Wm0     = (const float*)d_in[8];
  const float* Wm1     = (const float*)d_in[9];
  const float* Wm2     = (const float*)d_in[10];
  const float* Wm3     = (const float*)d_in[11];
  const float* W_lin0  = (const float*)d_in[12];
  const float* W_lin1  = (const float*)d_in[13];
  const float* W_skip0 = (const float*)d_in[14];
  const float* W_skip1 = (const float*)d_in[15];
  float* out = (float*)d_out;

  char* ws = (char*)d_ws;
  size_t off = 0;
  auto alloc = [&](size_t bytes) {
    void* p = ws + off;
    off = (off + bytes + 255) & ~(size_t)255;
    return p;
  };
  _Float16* UPH   = (_Float16*)alloc((size_t)NN * 512 * 2);
  _Float16* DOWNH = (_Float16*)alloc((size_t)NN * 64 * 2);
  _Float16* W0h   = (_Float16*)alloc(160 * 256 * 2);
  _Float16* W1h   = (_Float16*)alloc(256 * 256 * 2);
  _Float16* W2h   = (_Float16*)alloc(256 * 256 * 2);
  _Float16* W3h   = (_Float16*)alloc(256 * 512 * 2);
  _Float16* WL0h  = (_Float16*)alloc(256 * 128 * 2);
  _Float16* WL1h  = (_Float16*)alloc(256 * 128 * 2);
  int*      CNTS  = (int*)alloc((size_t)2 * NN * 4);  // CNT | CNT2, one memset
  int*      CNT   = CNTS;
  int*      CNT2  = CNTS + NN;
  int*      OFF   = (int*)alloc((size_t)(NN + 1) * 4);
  int*      CUR   = (int*)alloc((size_t)NN * 4);
  int*      EIDX  = (int*)alloc((size_t)NE * 4);
  int*      OFF2  = (int*)alloc((size_t)(NN + 1) * 4);
  int*      CUR2  = (int*)alloc((size_t)NN * 4);
  int*      SIDX  = (int*)alloc((size_t)NE * 4);
  _Float16* MIDs  = (_Float16*)alloc((size_t)NE * 512 * 2);

  hipMemsetAsync(CNTS, 0, (size_t)2 * NN * 4, stream);

  // scales folded into fp16 weights: 1/sqrt(136) layer0, 1/16 layers 1..3,
  // 1/256 for W_lin (includes sqrt(2C) and AVG_NEIGH).
  // prep = wconv (768 blocks) + node_pre (1250) + edge counting (625).
  prep<<<2643, 256, 0, stream>>>(Wm0, Wm1, Wm2, Wm3, W_lin0, W_lin1,
                                 W0h, W1h, W2h, W3h, WL0h, WL1h,
                                 node_feats, W_up0, W_skip0, W_down,
                                 W_up1, W_skip1,
                                 UPH, DOWNH, out + (size_t)NN * 512,
                                 edge_index, CNT, CNT2);

  k_scan2<<<2, 1024, 0, stream>>>(CNT, OFF, CUR, CNT2, OFF2, CUR2);
  k_fill2<<<625, 256, 0, stream>>>(edge_index, CUR, EIDX, CUR2, SIDX);

  edge_mlp<<<2500, 256, 0, stream>>>(edge_attrs, edge_feats, edge_index, SIDX,
                                     DOWNH, UPH, W0h, W1h, W2h, W3h, WL0h, WL1h,
                                     MIDs);
  gather_msg<<<NN, 256, 0, stream>>>(MIDs, OFF, EIDX, out);
}

// Round 7
// 457.655 us; speedup vs baseline: 1.2983x; 1.0083x over previous
//
#include <hip/hip_runtime.h>
#include <cmath>

#define NN 10000
#define NE 160000
#define INV_SQRT_C 0.08838834764831845f   // 1/sqrt(128)
#define INV_SQRT3F 0.5773502691896258f

typedef _Float16 f16x8 __attribute__((ext_vector_type(8)));
typedef _Float16 f16x4 __attribute__((ext_vector_type(4)));
typedef _Float16 f16x2 __attribute__((ext_vector_type(2)));
typedef float    f32x4 __attribute__((ext_vector_type(4)));

__device__ __forceinline__ float silu_f(float x) {
  return x / (1.f + __expf(-x));
}

// ---------------------------------------------------------------------------
// wconv9: all weight conversions (9 jobs) + edge-endpoint counting in ONE
// launch. Counting is independent of the conversions (reads edge_index only).
// Node GEMMs CANNOT be here: they read WS0h/WS1h/WDh written by this grid
// (no intra-grid ordering) — they live in prep2, launched after.
// B-fragment layout: storage slot ct*16+m within a P-chunk holds logical col
// m*(P/16)+ct (P=64: col=m*4+ct; P=16: identity).
// ---------------------------------------------------------------------------
__device__ __forceinline__ void wconv_one(
    int bx, const float* __restrict__ src, _Float16* __restrict__ dst,
    int Korig, int Kpad, int N, float scale, int P) {
  int total = Kpad * N;
  for (int t = bx * 256 + threadIdx.x; t < total; t += 128 * 256) {
    int n = t % N;
    int k = t / N;
    int kb = k >> 5, kk = k & 31;
    int sub = n & (P - 1);
    int n_l = (n & ~(P - 1)) | ((sub & 15) * (P >> 4) + (sub >> 4));
    float v = (k < Korig) ? src[(size_t)k * N + n_l] * scale : 0.f;
    dst[((size_t)(kb * N + n) << 5) + kk] = (_Float16)v;
  }
}

// [A | B] side-by-side as K=128 x N=256, P=64 (chunks never cross col 128)
__device__ __forceinline__ void wconv_pair(
    int bx, const float* __restrict__ A, const float* __restrict__ B,
    _Float16* __restrict__ dst, float scale) {
  int tgl = bx * 256 + threadIdx.x;          // 0..32767, exactly one elem
  int n = tgl & 255;
  int k = tgl >> 8;
  int kb = k >> 5, kk = k & 31;
  int sub = n & 63;
  int n_l = (n & ~63) | ((sub & 15) * 4 + (sub >> 4));
  float v = ((n_l < 128) ? A[(size_t)k * 128 + n_l]
                         : B[(size_t)k * 128 + (n_l - 128)]) * scale;
  dst[((size_t)(kb * 256 + n) << 5) + kk] = (_Float16)v;
}

// W_down: K=128 x N=64, P=16 (identity permutation)
__device__ __forceinline__ void wconv_dn(
    int bx, const float* __restrict__ src, _Float16* __restrict__ dst,
    float scale) {
  int tgl = bx * 256 + threadIdx.x;          // 0..8191, exactly one elem
  int n = tgl & 63;
  int k = tgl >> 6;
  int kb = k >> 5, kk = k & 31;
  float v = src[(size_t)k * 64 + n] * scale;
  dst[((size_t)(kb * 64 + n) << 5) + kk] = (_Float16)v;
}

__global__ __launch_bounds__(256) void wconv9(
    const float* __restrict__ s0, const float* __restrict__ s1,
    const float* __restrict__ s2, const float* __restrict__ s3,
    const float* __restrict__ s4, const float* __restrict__ s5,
    _Float16* __restrict__ d0, _Float16* __restrict__ d1,
    _Float16* __restrict__ d2, _Float16* __restrict__ d3,
    _Float16* __restrict__ d4, _Float16* __restrict__ d5,
    const float* __restrict__ W_up0, const float* __restrict__ W_skip0,
    const float* __restrict__ W_up1, const float* __restrict__ W_skip1,
    const float* __restrict__ W_down,
    _Float16* __restrict__ WS0h, _Float16* __restrict__ WS1h,
    _Float16* __restrict__ WDh,
    const int* __restrict__ edge_index,
    int* __restrict__ CNT, int* __restrict__ CNT2) {
  const int b = blockIdx.x;
  if (b < 768) {
    const int job = b >> 7, bx = b & 127;
    switch (job) {
      case 0: wconv_one(bx, s0, d0, 136, 160, 256, 0.08574929257125442f, 64); break;
      case 1: wconv_one(bx, s1, d1, 256, 256, 256, 0.0625f, 64); break;
      case 2: wconv_one(bx, s2, d2, 256, 256, 256, 0.0625f, 64); break;
      case 3: wconv_one(bx, s3, d3, 256, 256, 512, 0.0625f, 32); break;
      case 4: wconv_one(bx, s4, d4, 256, 256, 128, 1.0f / 256.0f, 32); break;
      default: wconv_one(bx, s5, d5, 256, 256, 128, 1.0f / 256.0f, 32); break;
    }
  } else if (b < 896) {
    wconv_pair(b - 768, W_up0, W_skip0, WS0h, INV_SQRT_C);
  } else if (b < 1024) {
    wconv_pair(b - 896, W_up1, W_skip1, WS1h, INV_SQRT_C);
  } else if (b < 1056) {
    wconv_dn(b - 1024, W_down, WDh, INV_SQRT_C);
  } else {
    int e = (b - 1056) * 256 + threadIdx.x;   // 625*256 = NE exactly
    if (e < NE) {
      int2 sr = *(const int2*)&edge_index[(size_t)e * 2];
      atomicAdd(&CNT[sr.y], 1);    // receiver
      atomicAdd(&CNT2[sr.x], 1);   // sender
    }
  }
}

// ---------------------------------------------------------------------------
// prep2: node pre-pass as MFMA GEMMs (was scalar VALU — 12k serial FMA-cycles
// per v-wave). Fragment conventions identical to edge_mlp's verified layers.
//   blocks [0,157):   s-GEMM  [64 nodes x 128] @ WS0h[128x256]=[up|skip]
//                     + WDh[128x64] (down), A-tile in LDS, XOR-swizzled
//   blocks [157,626): v-GEMM  rows=(n,c) pairs, [64 x 128] @ WS1h[128x256]
// A-tile swizzle: element (r,k) stored at block (k>>4)^(r&7) — without it
// the 16-lane stride-256B ds_read_b128 is a 16-way bank conflict.
// ---------------------------------------------------------------------------
__global__ __launch_bounds__(256) void prep2(
    const float* __restrict__ feats,
    const _Float16* __restrict__ WS0h, const _Float16* __restrict__ WS1h,
    const _Float16* __restrict__ WDh,
    _Float16* __restrict__ UPH, _Float16* __restrict__ DOWNH,
    float* __restrict__ out_sc) {
  __shared__ _Float16 As[64 * 128];   // 16 KB
  const int b = blockIdx.x;
  const int t = threadIdx.x;
  const int lane = t & 63;
  const int wv = t >> 6;
  const int m = lane & 15;
  const int g = lane >> 4;
  f32x4 zero4 = {0.f, 0.f, 0.f, 0.f};
  f16x8 zf = {0, 0, 0, 0, 0, 0, 0, 0};

  if (b < 157) {
    // ---------------- s-part: nodes n0..n0+63
    const int n0 = b * 64;
    for (int idx = t; idx < 1024; idx += 256) {
      int r = idx >> 4, c8 = idx & 15;     // 8-elem k-chunk
      int n = n0 + r;
      f16x8 av = zf;
      if (n < NN) {
        const float* src = &feats[(size_t)n * 512 + c8 * 8];
        float4 f0 = *(const float4*)src;
        float4 f1 = *(const float4*)(src + 4);
        av[0] = (_Float16)f0.x; av[1] = (_Float16)f0.y;
        av[2] = (_Float16)f0.z; av[3] = (_Float16)f0.w;
        av[4] = (_Float16)f1.x; av[5] = (_Float16)f1.y;
        av[6] = (_Float16)f1.z; av[7] = (_Float16)f1.w;
      }
      int sb = (c8 >> 1) ^ (r & 7);
      *(f16x8*)&As[r * 128 + (sb << 4) + (c8 & 1) * 8] = av;
    }
    __syncthreads();

    f32x4 acc[4][4];
    f32x4 acc2[4];
#pragma unroll
    for (int rt = 0; rt < 4; ++rt) {
      acc2[rt] = zero4;
#pragma unroll
      for (int ct = 0; ct < 4; ++ct) acc[rt][ct] = zero4;
    }
#pragma unroll
    for (int kb = 0; kb < 4; ++kb) {
      f16x8 a[4], bf[4];
#pragma unroll
      for (int rt = 0; rt < 4; ++rt) {
        int row = rt * 16 + m;
        a[rt] = *(const f16x8*)&As[row * 128 +
                 ((((kb * 2 + (g >> 1)) ^ (m & 7)) & 7) << 4) + (g & 1) * 8];
      }
#pragma unroll
      for (int ct = 0; ct < 4; ++ct)
        bf[ct] = *(const f16x8*)&WS0h[((size_t)(kb * 256 + wv * 64 + ct * 16 + m) << 5) + g * 8];
      f16x8 bd = *(const f16x8*)&WDh[((size_t)(kb * 64 + wv * 16 + m) << 5) + g * 8];
#pragma unroll
      for (int rt = 0; rt < 4; ++rt) {
#pragma unroll
        for (int ct = 0; ct < 4; ++ct)
          acc[rt][ct] = __builtin_amdgcn_mfma_f32_16x16x32_f16(a[rt], bf[ct], acc[rt][ct], 0, 0, 0);
        acc2[rt] = __builtin_amdgcn_mfma_f32_16x16x32_f16(a[rt], bd, acc2[rt], 0, 0, 0);
      }
    }
    // writeout: logical col within wave 64-chunk = m*4+ct (P=64); down: wv*16+m
#pragma unroll
    for (int rt = 0; rt < 4; ++rt)
#pragma unroll
      for (int q = 0; q < 4; ++q) {
        int row = rt * 16 + g * 4 + q;
        int n = n0 + row;
        if (n >= NN) continue;
        if (wv < 2) {
          f16x4 pk;
#pragma unroll
          for (int ct = 0; ct < 4; ++ct) pk[ct] = (_Float16)acc[rt][ct][q];
          *(f16x4*)&UPH[(size_t)n * 512 + wv * 64 + m * 4] = pk;
        } else {
          float4 p4 = {acc[rt][0][q], acc[rt][1][q], acc[rt][2][q], acc[rt][3][q]};
          *(float4*)&out_sc[(size_t)n * 512 + (wv - 2) * 64 + m * 4] = p4;
        }
        DOWNH[(size_t)n * 64 + wv * 16 + m] = (_Float16)acc2[rt][q];
      }
  } else if (b < 626) {
    // ---------------- v-part: rows are (n,c) pairs, rg = n*3+c
    const int v0 = (b - 157) * 64;
    for (int idx = t; idx < 1024; idx += 256) {
      int r = idx >> 4, c8 = idx & 15;
      int rg = v0 + r;
      f16x8 av = zf;
      if (rg < 3 * NN) {
        int n = rg / 3, c = rg - n * 3;
        const float* src = &feats[(size_t)n * 512 + 128 + c];
#pragma unroll
        for (int z = 0; z < 8; ++z) av[z] = (_Float16)src[(c8 * 8 + z) * 3];
      }
      int sb = (c8 >> 1) ^ (r & 7);
      *(f16x8*)&As[r * 128 + (sb << 4) + (c8 & 1) * 8] = av;
    }
    __syncthreads();

    f32x4 acc[4][4];
#pragma unroll
    for (int rt = 0; rt < 4; ++rt)
#pragma unroll
      for (int ct = 0; ct < 4; ++ct) acc[rt][ct] = zero4;
#pragma unroll
    for (int kb = 0; kb < 4; ++kb) {
      f16x8 a[4], bf[4];
#pragma unroll
      for (int rt = 0; rt < 4; ++rt) {
        int row = rt * 16 + m;
        a[rt] = *(const f16x8*)&As[row * 128 +
                 ((((kb * 2 + (g >> 1)) ^ (m & 7)) & 7) << 4) + (g & 1) * 8];
      }
#pragma unroll
      for (int ct = 0; ct < 4; ++ct)
        bf[ct] = *(const f16x8*)&WS1h[((size_t)(kb * 256 + wv * 64 + ct * 16 + m) << 5) + g * 8];
#pragma unroll
      for (int rt = 0; rt < 4; ++rt)
#pragma unroll
        for (int ct = 0; ct < 4; ++ct)
          acc[rt][ct] = __builtin_amdgcn_mfma_f32_16x16x32_f16(a[rt], bf[ct], acc[rt][ct], 0, 0, 0);
    }
#pragma unroll
    for (int rt = 0; rt < 4; ++rt)
#pragma unroll
      for (int q = 0; q < 4; ++q) {
        int row = rt * 16 + g * 4 + q;
        int rg = v0 + row;
        if (rg >= 3 * NN) continue;
        int n = rg / 3, c = rg - (rg / 3) * 3;
        if (wv < 2) {
#pragma unroll
          for (int ct = 0; ct < 4; ++ct) {
            int j = wv * 64 + m * 4 + ct;
            UPH[(size_t)n * 512 + 128 + j * 3 + c] = (_Float16)acc[rt][ct][q];
          }
        } else {
#pragma unroll
          for (int ct = 0; ct < 4; ++ct) {
            int j = (wv - 2) * 64 + m * 4 + ct;
            out_sc[(size_t)n * 512 + 128 + j * 3 + c] = acc[rt][ct][q];
          }
        }
      }
  }
}

// ---------------------------------------------------------------------------
// CSR scan + fill (verbatim round 4): scan launch grid=2 (both scans in
// parallel), fill writes EIDX = sender-sorted position for gather.
// ---------------------------------------------------------------------------
__device__ __forceinline__ void scan_one(const int* __restrict__ CNT,
                                         int* __restrict__ OFF,
                                         int* __restrict__ CUR, int* ts) {
  const int t = threadIdx.x;
  const int base = t * 10;
  int loc[10];
  int s = 0;
#pragma unroll
  for (int i = 0; i < 10; ++i) {
    int idx = base + i;
    int v = (idx < NN) ? CNT[idx] : 0;
    loc[i] = s;
    s += v;
  }
  ts[t] = s;
  __syncthreads();
  for (int off = 1; off < 1024; off <<= 1) {
    int v = (t >= off) ? ts[t - off] : 0;
    __syncthreads();
    ts[t] += v;
    __syncthreads();
  }
  int tp = (t > 0) ? ts[t - 1] : 0;
#pragma unroll
  for (int i = 0; i < 10; ++i) {
    int idx = base + i;
    if (idx < NN) {
      OFF[idx] = tp + loc[i];
      CUR[idx] = tp + loc[i];
    }
  }
  if (t == 1023) OFF[NN] = ts[1023];
}

__global__ __launch_bounds__(1024) void k_scan2(
    const int* __restrict__ CNT, int* __restrict__ OFF, int* __restrict__ CUR,
    const int* __restrict__ CNT2, int* __restrict__ OFF2, int* __restrict__ CUR2) {
  __shared__ int ts[1024];
  if (blockIdx.x == 0) scan_one(CNT, OFF, CUR, ts);
  else                 scan_one(CNT2, OFF2, CUR2, ts);
}

__global__ void k_fill2(const int* __restrict__ edge_index,
                        int* __restrict__ CUR, int* __restrict__ EIDX,
                        int* __restrict__ CUR2, int* __restrict__ SIDX) {
  int e = blockIdx.x * blockDim.x + threadIdx.x;
  if (e < NE) {
    int2 sr = *(const int2*)&edge_index[(size_t)e * 2];
    int ps = atomicAdd(&CUR2[sr.x], 1);  // sender-sorted position
    SIDX[ps] = e;
    int pr = atomicAdd(&CUR[sr.y], 1);   // receiver-CSR slot
    EIDX[pr] = ps;                       // gather reads MIDs[ps]
  }
}

// ---------------------------------------------------------------------------
// Fused edge kernel — round-0 verified structure (HA/HB ping-pong, SW/SP
// separate, original barrier schedule; 64 KB LDS, 2 blocks/CU, 128 VGPR).
// MIDs rows indexed by sender-sorted position (e0 + row) => contiguous per
// block. VERBATIM from round 4 (257.6 us, absmax 0.002).
// ---------------------------------------------------------------------------
__device__ __forceinline__ void mlp_layer_256(
    const _Float16* In, _Float16* Out, const _Float16* __restrict__ Wz,
    int m, int g, int wv) {
  f32x4 acc[4][4];
  f32x4 zero4 = {0.f, 0.f, 0.f, 0.f};
#pragma unroll
  for (int rt = 0; rt < 4; ++rt)
#pragma unroll
    for (int ct = 0; ct < 4; ++ct) acc[rt][ct] = zero4;

#pragma unroll
  for (int kb = 0; kb < 8; ++kb) {
    f16x8 a[4], b[4];
#pragma unroll
    for (int rt = 0; rt < 4; ++rt) {
      int row = rt * 16 + m;
      a[rt] = *(const f16x8*)&In[row * 256 + (((kb * 2 + (g >> 1)) ^ m) << 4) + (g & 1) * 8];
    }
#pragma unroll
    for (int ct = 0; ct < 4; ++ct)
      b[ct] = *(const f16x8*)&Wz[((size_t)(kb * 256 + wv * 64 + ct * 16 + m) << 5) + g * 8];
#pragma unroll
    for (int rt = 0; rt < 4; ++rt)
#pragma unroll
      for (int ct = 0; ct < 4; ++ct)
        acc[rt][ct] = __builtin_amdgcn_mfma_f32_16x16x32_f16(a[rt], b[ct], acc[rt][ct], 0, 0, 0);
  }
#pragma unroll
  for (int rt = 0; rt < 4; ++rt)
#pragma unroll
    for (int q = 0; q < 4; ++q) {
      int row = rt * 16 + g * 4 + q;
      f16x4 pk;
#pragma unroll
      for (int ct = 0; ct < 4; ++ct) pk[ct] = (_Float16)silu_f(acc[rt][ct][q]);
      int blk = (wv * 4 + (m >> 2)) ^ (row & 15);
      *(f16x4*)&Out[row * 256 + (blk << 4) + (m & 3) * 4] = pk;
    }
}

__global__ __launch_bounds__(256, 2) void edge_mlp(
    const float* __restrict__ edge_attrs,
    const float* __restrict__ edge_feats,
    const int* __restrict__ edge_index,
    const int* __restrict__ SIDX,
    const _Float16* __restrict__ DOWNH,
    const _Float16* __restrict__ UPH,
    const _Float16* __restrict__ W0h, const _Float16* __restrict__ W1h,
    const _Float16* __restrict__ W2h, const _Float16* __restrict__ W3h,
    const _Float16* __restrict__ WL0h, const _Float16* __restrict__ WL1h,
    _Float16* __restrict__ MIDs) {
  __shared__ _Float16 HA[64 * 256];
  __shared__ _Float16 HB[64 * 256];

  const int tid = threadIdx.x;
  const int lane = tid & 63;
  const int wv = tid >> 6;
  const int m = lane & 15;
  const int g = lane >> 4;
  const int e0 = blockIdx.x * 64;
  const int nw = wv * 64;

  int el_r[4], snd_r[4], rcv_r[4];
#pragma unroll
  for (int rt = 0; rt < 4; ++rt) {
    el_r[rt] = SIDX[e0 + rt * 16 + m];
    int2 sr = *(const int2*)&edge_index[(size_t)el_r[rt] * 2];
    snd_r[rt] = sr.x;
    rcv_r[rt] = sr.y;
  }

  f32x4 zero4 = {0.f, 0.f, 0.f, 0.f};
  f16x8 zf = {0, 0, 0, 0, 0, 0, 0, 0};

  // ---------------- layer 0: aug(136, padded 160) -> h1 (HA)
  {
    f32x4 acc[4][4];
#pragma unroll
    for (int rt = 0; rt < 4; ++rt)
#pragma unroll
      for (int ct = 0; ct < 4; ++ct) acc[rt][ct] = zero4;

#pragma unroll
    for (int kb = 0; kb < 5; ++kb) {
      const int k0 = kb * 32 + g * 8;
      f16x8 a[4], b[4];
#pragma unroll
      for (int rt = 0; rt < 4; ++rt) {
        if (k0 == 0) {
          const float* ef = &edge_feats[(size_t)el_r[rt] * 8];
          float4 f0 = *(const float4*)ef;
          float4 f1 = *(const float4*)(ef + 4);
          f16x8 av;
          av[0] = (_Float16)f0.x; av[1] = (_Float16)f0.y;
          av[2] = (_Float16)f0.z; av[3] = (_Float16)f0.w;
          av[4] = (_Float16)f1.x; av[5] = (_Float16)f1.y;
          av[6] = (_Float16)f1.z; av[7] = (_Float16)f1.w;
          a[rt] = av;
        } else if (k0 < 72) {
          a[rt] = *(const f16x8*)&DOWNH[(size_t)snd_r[rt] * 64 + (k0 - 8)];
        } else if (k0 < 136) {
          a[rt] = *(const f16x8*)&DOWNH[(size_t)rcv_r[rt] * 64 + (k0 - 72)];
        } else {
          a[rt] = zf;
        }
      }
#pragma unroll
      for (int ct = 0; ct < 4; ++ct)
        b[ct] = *(const f16x8*)&W0h[((size_t)(kb * 256 + nw + ct * 16 + m) << 5) + g * 8];
#pragma unroll
      for (int rt = 0; rt < 4; ++rt)
#pragma unroll
        for (int ct = 0; ct < 4; ++ct)
          acc[rt][ct] = __builtin_amdgcn_mfma_f32_16x16x32_f16(a[rt], b[ct], acc[rt][ct], 0, 0, 0);
    }
#pragma unroll
    for (int rt = 0; rt < 4; ++rt)
#pragma unroll
      for (int q = 0; q < 4; ++q) {
        int row = rt * 16 + g * 4 + q;
        f16x4 pk;
#pragma unroll
        for (int ct = 0; ct < 4; ++ct) pk[ct] = (_Float16)silu_f(acc[rt][ct][q]);
        int blk = (wv * 4 + (m >> 2)) ^ (row & 15);
        *(f16x4*)&HA[row * 256 + (blk << 4) + (m & 3) * 4] = pk;
      }
  }
  __syncthreads();

  mlp_layer_256(HA, HB, W1h, m, g, wv);   // layer 1: h1 -> h2
  __syncthreads();
  mlp_layer_256(HB, HA, W2h, m, g, wv);   // layer 2: h2 -> h3 (HA stays live)
  __syncthreads();

  // ================= epilogue =================
  _Float16* SW = HB;             // 64 x 128 fp16, tpw quarter
  _Float16* SP = HB + 64 * 128;  // 64 x 128 fp16, TP'd A-matrix

  const int e_loc = lane;
  const int ers = (e_loc ^ (e_loc >> 3)) & 7;
  const int elc = SIDX[e0 + e_loc];
  const int snd_e = edge_index[(size_t)elc * 2];
  const _Float16* uprow = &UPH[(size_t)snd_e * 512];

  // quarter GEMM into caller-provided acc buffer
  auto qgemm = [&](int qbase, f32x4 (&accq)[4][2]) {
#pragma unroll
    for (int rt = 0; rt < 4; ++rt)
#pragma unroll
      for (int ct = 0; ct < 2; ++ct) accq[rt][ct] = zero4;
#pragma unroll
    for (int kb = 0; kb < 8; ++kb) {
      f16x8 a[4], b[2];
#pragma unroll
      for (int rt = 0; rt < 4; ++rt) {
        int row = rt * 16 + m;
        a[rt] = *(const f16x8*)&HA[row * 256 + (((kb * 2 + (g >> 1)) ^ m) << 4) + (g & 1) * 8];
      }
#pragma unroll
      for (int ct = 0; ct < 2; ++ct)
        b[ct] = *(const f16x8*)&W3h[((size_t)(kb * 512 + qbase + wv * 32 + ct * 16 + m) << 5) + g * 8];
#pragma unroll
      for (int rt = 0; rt < 4; ++rt)
#pragma unroll
        for (int ct = 0; ct < 2; ++ct)
          accq[rt][ct] = __builtin_amdgcn_mfma_f32_16x16x32_f16(a[rt], b[ct], accq[rt][ct], 0, 0, 0);
    }
  };

  auto sw_write = [&](const f32x4 (&accq)[4][2]) {
#pragma unroll
    for (int rt = 0; rt < 4; ++rt)
#pragma unroll
      for (int r4 = 0; r4 < 4; ++r4) {
        int row = rt * 16 + g * 4 + r4;
        int rs = (row ^ (row >> 3)) & 7;
        f16x2 pk;
        pk[0] = (_Float16)accq[rt][0][r4];
        pk[1] = (_Float16)accq[rt][1][r4];
        int blk = ((wv * 2 + (m >> 3)) ^ rs) & 7;
        *(f16x2*)&SW[row * 128 + (blk << 4) + (m & 7) * 2] = pk;
      }
  };

  auto fold = [&](const _Float16* __restrict__ WLh, int qpart, f32x4 (&P)[4][2]) {
#pragma unroll
    for (int rt = 0; rt < 4; ++rt)
#pragma unroll
      for (int ct = 0; ct < 2; ++ct) P[rt][ct] = zero4;
#pragma unroll
    for (int kb = 0; kb < 4; ++kb) {
      f16x8 a[4], b[2];
#pragma unroll
      for (int rt = 0; rt < 4; ++rt) {
        int row = rt * 16 + m;
        int rs = (row ^ (row >> 3)) & 7;
        a[rt] = *(const f16x8*)&SP[row * 128 + ((((kb * 2 + (g >> 1)) ^ rs) & 7) << 4) + (g & 1) * 8];
      }
#pragma unroll
      for (int ct = 0; ct < 2; ++ct)
        b[ct] = *(const f16x8*)&WLh[((size_t)((qpart * 4 + kb) * 128 + wv * 32 + ct * 16 + m) << 5) + g * 8];
#pragma unroll
      for (int rt = 0; rt < 4; ++rt)
#pragma unroll
        for (int ct = 0; ct < 2; ++ct)
          P[rt][ct] = __builtin_amdgcn_mfma_f32_16x16x32_f16(a[rt], b[ct], P[rt][ct], 0, 0, 0);
    }
  };

  auto tp_xs = [&]() {
#pragma unroll
    for (int cch = 0; cch < 4; ++cch) {
      int ib = nw / 2 + cch * 8;
      int blk = ((ib >> 4) ^ ers) & 7;
      int off = e_loc * 128 + (blk << 4) + (ib & 15);
      f16x8 swv = *(const f16x8*)&SW[off];
      f16x8 upv = *(const f16x8*)&uprow[ib];
      f16x8 pr = swv * upv;
      *(f16x8*)&SP[off] = pr;
    }
  };

  _Float16 xvb[96];
  auto load_xv = [&]() {
#pragma unroll
    for (int u = 0; u < 12; ++u) {
      f16x8 t = *(const f16x8*)&uprow[128 + wv * 96 + u * 8];
#pragma unroll
      for (int z = 0; z < 8; ++z) xvb[u * 8 + z] = t[z];
    }
  };

  auto tp_w4 = [&]() {
    float4 ea = *(const float4*)&edge_attrs[(size_t)elc * 4];
#pragma unroll
    for (int cch = 0; cch < 4; ++cch) {
      int ib = nw / 2 + cch * 8;
      int blk = ((ib >> 4) ^ ers) & 7;
      int off = e_loc * 128 + (blk << 4) + (ib & 15);
      f16x8 swv = *(const f16x8*)&SW[off];
      f16x8 outv;
#pragma unroll
      for (int z = 0; z < 8; ++z) {
        int k = cch * 8 + z;
        float d = (float)xvb[k * 3] * ea.y + (float)xvb[k * 3 + 1] * ea.z +
                  (float)xvb[k * 3 + 2] * ea.w;
        outv[z] = (_Float16)((float)swv[z] * d);
      }
      *(f16x8*)&SP[off] = outv;
    }
  };

  auto tp_w3 = [&](int c) {
#pragma unroll
    for (int cch = 0; cch < 4; ++cch) {
      int ib = nw / 2 + cch * 8;
      int blk = ((ib >> 4) ^ ers) & 7;
      int off = e_loc * 128 + (blk << 4) + (ib & 15);
      f16x8 swv = *(const f16x8*)&SW[off];
      f16x8 outv;
#pragma unroll
      for (int z = 0; z < 8; ++z) {
        int k = cch * 8 + z;
        outv[z] = swv[z] * xvb[k * 3 + c];
      }
      *(f16x8*)&SP[off] = outv;
    }
  };

  f32x4 accqA[4][2], accqB[4][2];
  f32x4 P1[4][2], P4[4][2], P2[4][2], P3[4][2];

  // q1 (w1): A1 = w1 (x) xs ; P1 = A1 @ WL0a. Queue q4 gemm before barrier.
  qgemm(0, accqA);
  sw_write(accqA);
  tp_xs();
  qgemm(384, accqB);          // w4, independent — fills the barrier wait
  __syncthreads();            // B1: SP(A1) complete
  fold(WL0h, 0, P1);
  sw_write(accqB);            // SW <- w4 (SW(w1) readers all pre-B1)
  load_xv();
  __syncthreads();            // B2: all folds done reading SP(A1)
  tp_w4();
  qgemm(128, accqA);          // w2 queued
  __syncthreads();            // B3: SP(A4) complete
  fold(WL0h, 1, P4);
  sw_write(accqA);            // SW <- w2 (tp_w4 reads all pre-B3)

  // scalar part: MIDs[:, j] = y0*P1 + P4/sqrt(3). Row = sender-sorted pos.
#pragma unroll
  for (int rt = 0; rt < 4; ++rt)
#pragma unroll
    for (int r4 = 0; r4 < 4; ++r4) {
      int row = rt * 16 + g * 4 + r4;
      int elw = SIDX[e0 + row];
      float4 ea = *(const float4*)&edge_attrs[(size_t)elw * 4];
      f16x2 pk;
      pk[0] = (_Float16)(ea.x * P1[rt][0][r4] + INV_SQRT3F * P4[rt][0][r4]);
      pk[1] = (_Float16)(ea.x * P1[rt][1][r4] + INV_SQRT3F * P4[rt][1][r4]);
      *(f16x2*)&MIDs[(size_t)(e0 + row) * 512 + wv * 32 + m * 2] = pk;
    }
  __syncthreads();            // B4: folds done reading SP(A4)
  tp_xs();                    // SP <- A2 (reads SW(w2), own wave, pre-B4)
  qgemm(256, accqB);          // w3 queued
  __syncthreads();            // B5: SP(A2) complete
  fold(WL1h, 0, P2);
  sw_write(accqB);            // SW <- w3 (tp_xs reads all pre-B5)
  __syncthreads();            // B6: folds done reading SP(A2)

#pragma unroll
  for (int c = 0; c < 3; ++c) {
    tp_w3(c);                 // SP <- A3c (reads SW(w3), own wave)
    __syncthreads();          // SP complete
    fold(WL1h, 1, P3);
    // plane c: MIDs[:, 128 + c*128 + j] = yv[c]*P2 + y0*P3
#pragma unroll
    for (int rt = 0; rt < 4; ++rt)
#pragma unroll
      for (int r4 = 0; r4 < 4; ++r4) {
        int row = rt * 16 + g * 4 + r4;
        int elw = SIDX[e0 + row];
        float4 ea = *(const float4*)&edge_attrs[(size_t)elw * 4];
        float yvc = (c == 0) ? ea.y : (c == 1) ? ea.z : ea.w;
        f16x2 pk;
        pk[0] = (_Float16)(yvc * P2[rt][0][r4] + ea.x * P3[rt][0][r4]);
        pk[1] = (_Float16)(yvc * P2[rt][1][r4] + ea.x * P3[rt][1][r4]);
        *(f16x2*)&MIDs[(size_t)(e0 + row) * 512 + 128 + c * 128 + wv * 32 + m * 2] = pk;
      }
    if (c < 2) __syncthreads();  // folds done reading SP before next tp_w3
  }
}

// ---------------------------------------------------------------------------
// Gather: one block per node; LDS-staged edge ids + 4-way unroll; output row
// staged in LDS and stored coalesced (float2/lane). EIDX holds sender-sorted
// positions => MIDs rows are contiguous per edge_mlp block.
// ---------------------------------------------------------------------------
__global__ __launch_bounds__(256) void gather_msg(
    const _Float16* __restrict__ MIDs, const int* __restrict__ OFF,
    const int* __restrict__ EIDX, float* __restrict__ out) {
  __shared__ int eb[256];
  __shared__ float os[512];
  const int n = blockIdx.x;
  const int t = threadIdx.x;
  const int beg = OFF[n], end = OFF[n + 1];
  float a0 = 0.f, a1 = 0.f;
  for (int base = beg; base < end; base += 256) {
    int cnt = min(256, end - base);
    __syncthreads();
    if (t < cnt) eb[t] = EIDX[base + t];
    __syncthreads();
    int k = 0;
    for (; k + 4 <= cnt; k += 4) {
      int e0_ = eb[k], e1_ = eb[k + 1], e2_ = eb[k + 2], e3_ = eb[k + 3];
      f16x2 v0 = *(const f16x2*)&MIDs[(size_t)e0_ * 512 + t * 2];
      f16x2 v1 = *(const f16x2*)&MIDs[(size_t)e1_ * 512 + t * 2];
      f16x2 v2 = *(const f16x2*)&MIDs[(size_t)e2_ * 512 + t * 2];
      f16x2 v3 = *(const f16x2*)&MIDs[(size_t)e3_ * 512 + t * 2];
      a0 += (float)v0[0] + (float)v1[0] + (float)v2[0] + (float)v3[0];
      a1 += (float)v0[1] + (float)v1[1] + (float)v2[1] + (float)v3[1];
    }
    for (; k < cnt; ++k) {
      f16x2 v = *(const f16x2*)&MIDs[(size_t)eb[k] * 512 + t * 2];
      a0 += (float)v[0];
      a1 += (float)v[1];
    }
  }
#pragma unroll
  for (int u = 0; u < 2; ++u) {
    int x = t * 2 + u;
    float a = u ? a1 : a0;
    int dst;
    if (x < 128) {
      dst = x * 4;
    } else {
      int xm = x - 128;
      int c = xm >> 7, j = xm & 127;
      dst = j * 4 + 1 + c;
    }
    os[dst] = a;
  }
  __syncthreads();
  *(float2*)&out[(size_t)n * 512 + t * 2] = *(const float2*)&os[t * 2];
}

// ---------------------------------------------------------------------------
extern "C" void kernel_launch(void* const* d_in, const int* in_sizes, int n_in,
                              void* d_out, int out_size, void* d_ws, size_t ws_size,
                              hipStream_t stream) {
  const float* node_feats = (const float*)d_in[1];
  const float* edge_attrs = (const float*)d_in[2];
  const float* edge_feats = (const float*)d_in[3];
  const int*   edge_index = (const int*)d_in[4];
  const float* W_up0   = (const float*)d_in[5];
  const float* W_up1   = (const float*)d_in[6];
  const float* W_down  = (const float*)d_in[7];
  const float* Wm0     = (const float*)d_in[8];
  const float* Wm1     = (const float*)d_in[9];
  const float* Wm2     = (const float*)d_in[10];
  const float* Wm3     = (const float*)d_in[11];
  const float* W_lin0  = (const float*)d_in[12];
  const float* W_lin1  = (const float*)d_in[13];
  const float* W_skip0 = (const float*)d_in[14];
  const float* W_skip1 = (const float*)d_in[15];
  float* out = (float*)d_out;

  char* ws = (char*)d_ws;
  size_t off = 0;
  auto alloc = [&](size_t bytes) {
    void* p = ws + off;
    off = (off + bytes + 255) & ~(size_t)255;
    return p;
  };
  _Float16* UPH   = (_Float16*)alloc((size_t)NN * 512 * 2);
  _Float16* DOWNH = (_Float16*)alloc((size_t)NN * 64 * 2);
  _Float16* W0h   = (_Float16*)alloc(160 * 256 * 2);
  _Float16* W1h   = (_Float16*)alloc(256 * 256 * 2);
  _Float16* W2h   = (_Float16*)alloc(256 * 256 * 2);
  _Float16* W3h   = (_Float16*)alloc(256 * 512 * 2);
  _Float16* WL0h  = (_Float16*)alloc(256 * 128 * 2);
  _Float16* WL1h  = (_Float16*)alloc(256 * 128 * 2);
  _Float16* WS0h  = (_Float16*)alloc(128 * 256 * 2);  // [Wup0|Wskip0]
  _Float16* WS1h  = (_Float16*)alloc(128 * 256 * 2);  // [Wup1|Wskip1]
  _Float16* WDh   = (_Float16*)alloc(128 * 64 * 2);   // Wdown
  int*      CNTS  = (int*)alloc((size_t)2 * NN * 4);  // CNT | CNT2, one memset
  int*      CNT   = CNTS;
  int*      CNT2  = CNTS + NN;
  int*      OFF   = (int*)alloc((size_t)(NN + 1) * 4);
  int*      CUR   = (int*)alloc((size_t)NN * 4);
  int*      EIDX  = (int*)alloc((size_t)NE * 4);
  int*      OFF2  = (int*)alloc((size_t)(NN + 1) * 4);
  int*      CUR2  = (int*)alloc((size_t)NN * 4);
  int*      SIDX  = (int*)alloc((size_t)NE * 4);
  _Float16* MIDs  = (_Float16*)alloc((size_t)NE * 512 * 2);

  hipMemsetAsync(CNTS, 0, (size_t)2 * NN * 4, stream);

  // wconv9 = 9 weight conversions (1056 blocks) + edge counting (625).
  // Node GEMMs must come AFTER (they read WS0h/WS1h/WDh).
  wconv9<<<1681, 256, 0, stream>>>(Wm0, Wm1, Wm2, Wm3, W_lin0, W_lin1,
                                   W0h, W1h, W2h, W3h, WL0h, WL1h,
                                   W_up0, W_skip0, W_up1, W_skip1, W_down,
                                   WS0h, WS1h, WDh,
                                   edge_index, CNT, CNT2);

  // node pre-pass as MFMA GEMMs (157 s-blocks + 469 v-blocks)
  prep2<<<626, 256, 0, stream>>>(node_feats, WS0h, WS1h, WDh,
                                 UPH, DOWNH, out + (size_t)NN * 512);

  k_scan2<<<2, 1024, 0, stream>>>(CNT, OFF, CUR, CNT2, OFF2, CUR2);
  k_fill2<<<625, 256, 0, stream>>>(edge_index, CUR, EIDX, CUR2, SIDX);

  edge_mlp<<<2500, 256, 0, stream>>>(edge_attrs, edge_feats, edge_index, SIDX,
                                     DOWNH, UPH, W0h, W1h, W2h, W3h, WL0h, WL1h,
                                     MIDs);
  gather_msg<<<NN, 256, 0, stream>>>(MIDs, OFF, EIDX, out);
}

// Round 8
// 443.457 us; speedup vs baseline: 1.3399x; 1.0320x over previous
//
#include <hip/hip_runtime.h>
#include <cmath>

#define NN 10000
#define NE 160000
#define INV_SQRT_C 0.08838834764831845f   // 1/sqrt(128)
#define INV_SQRT3F 0.5773502691896258f

typedef _Float16 f16x8 __attribute__((ext_vector_type(8)));
typedef _Float16 f16x4 __attribute__((ext_vector_type(4)));
typedef _Float16 f16x2 __attribute__((ext_vector_type(2)));
typedef float    f32x4 __attribute__((ext_vector_type(4)));

__device__ __forceinline__ float silu_f(float x) {
  return x / (1.f + __expf(-x));
}

// ---------------------------------------------------------------------------
// wconv9: all weight conversions (9 jobs) + edge-endpoint counting in ONE
// launch. Node GEMMs live in prep2 (they read WS0h/WS1h/WDh — no intra-grid
// ordering). B-fragment layout: storage slot ct*16+m within a P-chunk holds
// logical col m*(P/16)+ct.
// ---------------------------------------------------------------------------
__device__ __forceinline__ void wconv_one(
    int bx, const float* __restrict__ src, _Float16* __restrict__ dst,
    int Korig, int Kpad, int N, float scale, int P) {
  int total = Kpad * N;
  for (int t = bx * 256 + threadIdx.x; t < total; t += 128 * 256) {
    int n = t % N;
    int k = t / N;
    int kb = k >> 5, kk = k & 31;
    int sub = n & (P - 1);
    int n_l = (n & ~(P - 1)) | ((sub & 15) * (P >> 4) + (sub >> 4));
    float v = (k < Korig) ? src[(size_t)k * N + n_l] * scale : 0.f;
    dst[((size_t)(kb * N + n) << 5) + kk] = (_Float16)v;
  }
}

// [A | B] side-by-side as K=128 x N=256, P=64 (chunks never cross col 128)
__device__ __forceinline__ void wconv_pair(
    int bx, const float* __restrict__ A, const float* __restrict__ B,
    _Float16* __restrict__ dst, float scale) {
  int tgl = bx * 256 + threadIdx.x;          // 0..32767, exactly one elem
  int n = tgl & 255;
  int k = tgl >> 8;
  int kb = k >> 5, kk = k & 31;
  int sub = n & 63;
  int n_l = (n & ~63) | ((sub & 15) * 4 + (sub >> 4));
  float v = ((n_l < 128) ? A[(size_t)k * 128 + n_l]
                         : B[(size_t)k * 128 + (n_l - 128)]) * scale;
  dst[((size_t)(kb * 256 + n) << 5) + kk] = (_Float16)v;
}

// W_down: K=128 x N=64, P=16 (identity permutation)
__device__ __forceinline__ void wconv_dn(
    int bx, const float* __restrict__ src, _Float16* __restrict__ dst,
    float scale) {
  int tgl = bx * 256 + threadIdx.x;          // 0..8191, exactly one elem
  int n = tgl & 63;
  int k = tgl >> 6;
  int kb = k >> 5, kk = k & 31;
  float v = src[(size_t)k * 64 + n] * scale;
  dst[((size_t)(kb * 64 + n) << 5) + kk] = (_Float16)v;
}

__global__ __launch_bounds__(256) void wconv9(
    const float* __restrict__ s0, const float* __restrict__ s1,
    const float* __restrict__ s2, const float* __restrict__ s3,
    const float* __restrict__ s4, const float* __restrict__ s5,
    _Float16* __restrict__ d0, _Float16* __restrict__ d1,
    _Float16* __restrict__ d2, _Float16* __restrict__ d3,
    _Float16* __restrict__ d4, _Float16* __restrict__ d5,
    const float* __restrict__ W_up0, const float* __restrict__ W_skip0,
    const float* __restrict__ W_up1, const float* __restrict__ W_skip1,
    const float* __restrict__ W_down,
    _Float16* __restrict__ WS0h, _Float16* __restrict__ WS1h,
    _Float16* __restrict__ WDh,
    const int* __restrict__ edge_index,
    int* __restrict__ CNT, int* __restrict__ CNT2) {
  const int b = blockIdx.x;
  if (b < 768) {
    const int job = b >> 7, bx = b & 127;
    switch (job) {
      case 0: wconv_one(bx, s0, d0, 136, 160, 256, 0.08574929257125442f, 64); break;
      case 1: wconv_one(bx, s1, d1, 256, 256, 256, 0.0625f, 64); break;
      case 2: wconv_one(bx, s2, d2, 256, 256, 256, 0.0625f, 64); break;
      case 3: wconv_one(bx, s3, d3, 256, 256, 512, 0.0625f, 32); break;
      case 4: wconv_one(bx, s4, d4, 256, 256, 128, 1.0f / 256.0f, 32); break;
      default: wconv_one(bx, s5, d5, 256, 256, 128, 1.0f / 256.0f, 32); break;
    }
  } else if (b < 896) {
    wconv_pair(b - 768, W_up0, W_skip0, WS0h, INV_SQRT_C);
  } else if (b < 1024) {
    wconv_pair(b - 896, W_up1, W_skip1, WS1h, INV_SQRT_C);
  } else if (b < 1056) {
    wconv_dn(b - 1024, W_down, WDh, INV_SQRT_C);
  } else {
    int e = (b - 1056) * 256 + threadIdx.x;   // 625*256 = NE exactly
    if (e < NE) {
      int2 sr = *(const int2*)&edge_index[(size_t)e * 2];
      atomicAdd(&CNT[sr.y], 1);    // receiver
      atomicAdd(&CNT2[sr.x], 1);   // sender
    }
  }
}

// ---------------------------------------------------------------------------
// prep2: node pre-pass as MFMA GEMMs. Fragment conventions identical to
// edge_mlp's verified layers. A-tile XOR-swizzled in LDS.
// ---------------------------------------------------------------------------
__global__ __launch_bounds__(256) void prep2(
    const float* __restrict__ feats,
    const _Float16* __restrict__ WS0h, const _Float16* __restrict__ WS1h,
    const _Float16* __restrict__ WDh,
    _Float16* __restrict__ UPH, _Float16* __restrict__ DOWNH,
    float* __restrict__ out_sc) {
  __shared__ _Float16 As[64 * 128];   // 16 KB
  const int b = blockIdx.x;
  const int t = threadIdx.x;
  const int lane = t & 63;
  const int wv = t >> 6;
  const int m = lane & 15;
  const int g = lane >> 4;
  f32x4 zero4 = {0.f, 0.f, 0.f, 0.f};
  f16x8 zf = {0, 0, 0, 0, 0, 0, 0, 0};

  if (b < 157) {
    // ---------------- s-part: nodes n0..n0+63
    const int n0 = b * 64;
    for (int idx = t; idx < 1024; idx += 256) {
      int r = idx >> 4, c8 = idx & 15;     // 8-elem k-chunk
      int n = n0 + r;
      f16x8 av = zf;
      if (n < NN) {
        const float* src = &feats[(size_t)n * 512 + c8 * 8];
        float4 f0 = *(const float4*)src;
        float4 f1 = *(const float4*)(src + 4);
        av[0] = (_Float16)f0.x; av[1] = (_Float16)f0.y;
        av[2] = (_Float16)f0.z; av[3] = (_Float16)f0.w;
        av[4] = (_Float16)f1.x; av[5] = (_Float16)f1.y;
        av[6] = (_Float16)f1.z; av[7] = (_Float16)f1.w;
      }
      int sb = (c8 >> 1) ^ (r & 7);
      *(f16x8*)&As[r * 128 + (sb << 4) + (c8 & 1) * 8] = av;
    }
    __syncthreads();

    f32x4 acc[4][4];
    f32x4 acc2[4];
#pragma unroll
    for (int rt = 0; rt < 4; ++rt) {
      acc2[rt] = zero4;
#pragma unroll
      for (int ct = 0; ct < 4; ++ct) acc[rt][ct] = zero4;
    }
#pragma unroll
    for (int kb = 0; kb < 4; ++kb) {
      f16x8 a[4], bf[4];
#pragma unroll
      for (int rt = 0; rt < 4; ++rt) {
        int row = rt * 16 + m;
        a[rt] = *(const f16x8*)&As[row * 128 +
                 ((((kb * 2 + (g >> 1)) ^ (m & 7)) & 7) << 4) + (g & 1) * 8];
      }
#pragma unroll
      for (int ct = 0; ct < 4; ++ct)
        bf[ct] = *(const f16x8*)&WS0h[((size_t)(kb * 256 + wv * 64 + ct * 16 + m) << 5) + g * 8];
      f16x8 bd = *(const f16x8*)&WDh[((size_t)(kb * 64 + wv * 16 + m) << 5) + g * 8];
#pragma unroll
      for (int rt = 0; rt < 4; ++rt) {
#pragma unroll
        for (int ct = 0; ct < 4; ++ct)
          acc[rt][ct] = __builtin_amdgcn_mfma_f32_16x16x32_f16(a[rt], bf[ct], acc[rt][ct], 0, 0, 0);
        acc2[rt] = __builtin_amdgcn_mfma_f32_16x16x32_f16(a[rt], bd, acc2[rt], 0, 0, 0);
      }
    }
#pragma unroll
    for (int rt = 0; rt < 4; ++rt)
#pragma unroll
      for (int q = 0; q < 4; ++q) {
        int row = rt * 16 + g * 4 + q;
        int n = n0 + row;
        if (n >= NN) continue;
        if (wv < 2) {
          f16x4 pk;
#pragma unroll
          for (int ct = 0; ct < 4; ++ct) pk[ct] = (_Float16)acc[rt][ct][q];
          *(f16x4*)&UPH[(size_t)n * 512 + wv * 64 + m * 4] = pk;
        } else {
          float4 p4 = {acc[rt][0][q], acc[rt][1][q], acc[rt][2][q], acc[rt][3][q]};
          *(float4*)&out_sc[(size_t)n * 512 + (wv - 2) * 64 + m * 4] = p4;
        }
        DOWNH[(size_t)n * 64 + wv * 16 + m] = (_Float16)acc2[rt][q];
      }
  } else if (b < 626) {
    // ---------------- v-part: rows are (n,c) pairs, rg = n*3+c
    const int v0 = (b - 157) * 64;
    for (int idx = t; idx < 1024; idx += 256) {
      int r = idx >> 4, c8 = idx & 15;
      int rg = v0 + r;
      f16x8 av = zf;
      if (rg < 3 * NN) {
        int n = rg / 3, c = rg - n * 3;
        const float* src = &feats[(size_t)n * 512 + 128 + c];
#pragma unroll
        for (int z = 0; z < 8; ++z) av[z] = (_Float16)src[(c8 * 8 + z) * 3];
      }
      int sb = (c8 >> 1) ^ (r & 7);
      *(f16x8*)&As[r * 128 + (sb << 4) + (c8 & 1) * 8] = av;
    }
    __syncthreads();

    f32x4 acc[4][4];
#pragma unroll
    for (int rt = 0; rt < 4; ++rt)
#pragma unroll
      for (int ct = 0; ct < 4; ++ct) acc[rt][ct] = zero4;
#pragma unroll
    for (int kb = 0; kb < 4; ++kb) {
      f16x8 a[4], bf[4];
#pragma unroll
      for (int rt = 0; rt < 4; ++rt) {
        int row = rt * 16 + m;
        a[rt] = *(const f16x8*)&As[row * 128 +
                 ((((kb * 2 + (g >> 1)) ^ (m & 7)) & 7) << 4) + (g & 1) * 8];
      }
#pragma unroll
      for (int ct = 0; ct < 4; ++ct)
        bf[ct] = *(const f16x8*)&WS1h[((size_t)(kb * 256 + wv * 64 + ct * 16 + m) << 5) + g * 8];
#pragma unroll
      for (int rt = 0; rt < 4; ++rt)
#pragma unroll
        for (int ct = 0; ct < 4; ++ct)
          acc[rt][ct] = __builtin_amdgcn_mfma_f32_16x16x32_f16(a[rt], bf[ct], acc[rt][ct], 0, 0, 0);
    }
#pragma unroll
    for (int rt = 0; rt < 4; ++rt)
#pragma unroll
      for (int q = 0; q < 4; ++q) {
        int row = rt * 16 + g * 4 + q;
        int rg = v0 + row;
        if (rg >= 3 * NN) continue;
        int n = rg / 3, c = rg - (rg / 3) * 3;
        if (wv < 2) {
#pragma unroll
          for (int ct = 0; ct < 4; ++ct) {
            int j = wv * 64 + m * 4 + ct;
            UPH[(size_t)n * 512 + 128 + j * 3 + c] = (_Float16)acc[rt][ct][q];
          }
        } else {
#pragma unroll
          for (int ct = 0; ct < 4; ++ct) {
            int j = (wv - 2) * 64 + m * 4 + ct;
            out_sc[(size_t)n * 512 + 128 + j * 3 + c] = acc[rt][ct][q];
          }
        }
      }
  }
}

// ---------------------------------------------------------------------------
// CSR scan + fill (verbatim round 4).
// ---------------------------------------------------------------------------
__device__ __forceinline__ void scan_one(const int* __restrict__ CNT,
                                         int* __restrict__ OFF,
                                         int* __restrict__ CUR, int* ts) {
  const int t = threadIdx.x;
  const int base = t * 10;
  int loc[10];
  int s = 0;
#pragma unroll
  for (int i = 0; i < 10; ++i) {
    int idx = base + i;
    int v = (idx < NN) ? CNT[idx] : 0;
    loc[i] = s;
    s += v;
  }
  ts[t] = s;
  __syncthreads();
  for (int off = 1; off < 1024; off <<= 1) {
    int v = (t >= off) ? ts[t - off] : 0;
    __syncthreads();
    ts[t] += v;
    __syncthreads();
  }
  int tp = (t > 0) ? ts[t - 1] : 0;
#pragma unroll
  for (int i = 0; i < 10; ++i) {
    int idx = base + i;
    if (idx < NN) {
      OFF[idx] = tp + loc[i];
      CUR[idx] = tp + loc[i];
    }
  }
  if (t == 1023) OFF[NN] = ts[1023];
}

__global__ __launch_bounds__(1024) void k_scan2(
    const int* __restrict__ CNT, int* __restrict__ OFF, int* __restrict__ CUR,
    const int* __restrict__ CNT2, int* __restrict__ OFF2, int* __restrict__ CUR2) {
  __shared__ int ts[1024];
  if (blockIdx.x == 0) scan_one(CNT, OFF, CUR, ts);
  else                 scan_one(CNT2, OFF2, CUR2, ts);
}

__global__ void k_fill2(const int* __restrict__ edge_index,
                        int* __restrict__ CUR, int* __restrict__ EIDX,
                        int* __restrict__ CUR2, int* __restrict__ SIDX) {
  int e = blockIdx.x * blockDim.x + threadIdx.x;
  if (e < NE) {
    int2 sr = *(const int2*)&edge_index[(size_t)e * 2];
    int ps = atomicAdd(&CUR2[sr.x], 1);  // sender-sorted position
    SIDX[ps] = e;
    int pr = atomicAdd(&CUR[sr.y], 1);   // receiver-CSR slot
    EIDX[pr] = ps;                       // gather reads MIDs[ps]
  }
}

// ---------------------------------------------------------------------------
// Fused edge kernel — round-0 verified structure (HA/HB ping-pong, SW/SP
// separate, original barrier schedule; 2 blocks/CU, 128 VGPR). MIDs rows
// indexed by sender-sorted position (e0 + row) => contiguous per block.
// New this round: per-block epilogue metadata (SIDX, sender, edge_attrs)
// staged once into 1.5 KB LDS (written by tid<64 before the first barrier,
// read only after it) — removes the scattered SIDX/edge_index/edge_attrs
// loads from the barrier-separated epilogue sections, and re-rolls codegen
// (round-7's +55 us on verbatim code = co-compiled-kernel schedule
// perturbation, learn_hip rule #19).
// ---------------------------------------------------------------------------
__device__ __forceinline__ void mlp_layer_256(
    const _Float16* In, _Float16* Out, const _Float16* __restrict__ Wz,
    int m, int g, int wv) {
  f32x4 acc[4][4];
  f32x4 zero4 = {0.f, 0.f, 0.f, 0.f};
#pragma unroll
  for (int rt = 0; rt < 4; ++rt)
#pragma unroll
    for (int ct = 0; ct < 4; ++ct) acc[rt][ct] = zero4;

#pragma unroll
  for (int kb = 0; kb < 8; ++kb) {
    f16x8 a[4], b[4];
#pragma unroll
    for (int rt = 0; rt < 4; ++rt) {
      int row = rt * 16 + m;
      a[rt] = *(const f16x8*)&In[row * 256 + (((kb * 2 + (g >> 1)) ^ m) << 4) + (g & 1) * 8];
    }
#pragma unroll
    for (int ct = 0; ct < 4; ++ct)
      b[ct] = *(const f16x8*)&Wz[((size_t)(kb * 256 + wv * 64 + ct * 16 + m) << 5) + g * 8];
#pragma unroll
    for (int rt = 0; rt < 4; ++rt)
#pragma unroll
      for (int ct = 0; ct < 4; ++ct)
        acc[rt][ct] = __builtin_amdgcn_mfma_f32_16x16x32_f16(a[rt], b[ct], acc[rt][ct], 0, 0, 0);
  }
#pragma unroll
  for (int rt = 0; rt < 4; ++rt)
#pragma unroll
    for (int q = 0; q < 4; ++q) {
      int row = rt * 16 + g * 4 + q;
      f16x4 pk;
#pragma unroll
      for (int ct = 0; ct < 4; ++ct) pk[ct] = (_Float16)silu_f(acc[rt][ct][q]);
      int blk = (wv * 4 + (m >> 2)) ^ (row & 15);
      *(f16x4*)&Out[row * 256 + (blk << 4) + (m & 3) * 4] = pk;
    }
}

__global__ __launch_bounds__(256, 2) void edge_mlp(
    const float* __restrict__ edge_attrs,
    const float* __restrict__ edge_feats,
    const int* __restrict__ edge_index,
    const int* __restrict__ SIDX,
    const _Float16* __restrict__ DOWNH,
    const _Float16* __restrict__ UPH,
    const _Float16* __restrict__ W0h, const _Float16* __restrict__ W1h,
    const _Float16* __restrict__ W2h, const _Float16* __restrict__ W3h,
    const _Float16* __restrict__ WL0h, const _Float16* __restrict__ WL1h,
    _Float16* __restrict__ MIDs) {
  __shared__ _Float16 HA[64 * 256];
  __shared__ _Float16 HB[64 * 256];
  __shared__ int    SNDs[64];
  __shared__ float4 EAs[64];

  const int tid = threadIdx.x;
  const int lane = tid & 63;
  const int wv = tid >> 6;
  const int m = lane & 15;
  const int g = lane >> 4;
  const int e0 = blockIdx.x * 64;
  const int nw = wv * 64;

  // stage epilogue metadata (visible after the first barrier)
  if (tid < 64) {
    int el = SIDX[e0 + tid];
    SNDs[tid] = edge_index[(size_t)el * 2];
    EAs[tid] = *(const float4*)&edge_attrs[(size_t)el * 4];
  }

  int el_r[4], snd_r[4], rcv_r[4];
#pragma unroll
  for (int rt = 0; rt < 4; ++rt) {
    el_r[rt] = SIDX[e0 + rt * 16 + m];
    int2 sr = *(const int2*)&edge_index[(size_t)el_r[rt] * 2];
    snd_r[rt] = sr.x;
    rcv_r[rt] = sr.y;
  }

  f32x4 zero4 = {0.f, 0.f, 0.f, 0.f};
  f16x8 zf = {0, 0, 0, 0, 0, 0, 0, 0};

  // ---------------- layer 0: aug(136, padded 160) -> h1 (HA)
  {
    f32x4 acc[4][4];
#pragma unroll
    for (int rt = 0; rt < 4; ++rt)
#pragma unroll
      for (int ct = 0; ct < 4; ++ct) acc[rt][ct] = zero4;

#pragma unroll
    for (int kb = 0; kb < 5; ++kb) {
      const int k0 = kb * 32 + g * 8;
      f16x8 a[4], b[4];
#pragma unroll
      for (int rt = 0; rt < 4; ++rt) {
        if (k0 == 0) {
          const float* ef = &edge_feats[(size_t)el_r[rt] * 8];
          float4 f0 = *(const float4*)ef;
          float4 f1 = *(const float4*)(ef + 4);
          f16x8 av;
          av[0] = (_Float16)f0.x; av[1] = (_Float16)f0.y;
          av[2] = (_Float16)f0.z; av[3] = (_Float16)f0.w;
          av[4] = (_Float16)f1.x; av[5] = (_Float16)f1.y;
          av[6] = (_Float16)f1.z; av[7] = (_Float16)f1.w;
          a[rt] = av;
        } else if (k0 < 72) {
          a[rt] = *(const f16x8*)&DOWNH[(size_t)snd_r[rt] * 64 + (k0 - 8)];
        } else if (k0 < 136) {
          a[rt] = *(const f16x8*)&DOWNH[(size_t)rcv_r[rt] * 64 + (k0 - 72)];
        } else {
          a[rt] = zf;
        }
      }
#pragma unroll
      for (int ct = 0; ct < 4; ++ct)
        b[ct] = *(const f16x8*)&W0h[((size_t)(kb * 256 + nw + ct * 16 + m) << 5) + g * 8];
#pragma unroll
      for (int rt = 0; rt < 4; ++rt)
#pragma unroll
        for (int ct = 0; ct < 4; ++ct)
          acc[rt][ct] = __builtin_amdgcn_mfma_f32_16x16x32_f16(a[rt], b[ct], acc[rt][ct], 0, 0, 0);
    }
#pragma unroll
    for (int rt = 0; rt < 4; ++rt)
#pragma unroll
      for (int q = 0; q < 4; ++q) {
        int row = rt * 16 + g * 4 + q;
        f16x4 pk;
#pragma unroll
        for (int ct = 0; ct < 4; ++ct) pk[ct] = (_Float16)silu_f(acc[rt][ct][q]);
        int blk = (wv * 4 + (m >> 2)) ^ (row & 15);
        *(f16x4*)&HA[row * 256 + (blk << 4) + (m & 3) * 4] = pk;
      }
  }
  __syncthreads();

  mlp_layer_256(HA, HB, W1h, m, g, wv);   // layer 1: h1 -> h2
  __syncthreads();
  mlp_layer_256(HB, HA, W2h, m, g, wv);   // layer 2: h2 -> h3 (HA stays live)
  __syncthreads();

  // ================= epilogue =================
  _Float16* SW = HB;             // 64 x 128 fp16, tpw quarter
  _Float16* SP = HB + 64 * 128;  // 64 x 128 fp16, TP'd A-matrix

  const int e_loc = lane;
  const int ers = (e_loc ^ (e_loc >> 3)) & 7;
  const int snd_e = SNDs[e_loc];
  const _Float16* uprow = &UPH[(size_t)snd_e * 512];

  // quarter GEMM into caller-provided acc buffer
  auto qgemm = [&](int qbase, f32x4 (&accq)[4][2]) {
#pragma unroll
    for (int rt = 0; rt < 4; ++rt)
#pragma unroll
      for (int ct = 0; ct < 2; ++ct) accq[rt][ct] = zero4;
#pragma unroll
    for (int kb = 0; kb < 8; ++kb) {
      f16x8 a[4], b[2];
#pragma unroll
      for (int rt = 0; rt < 4; ++rt) {
        int row = rt * 16 + m;
        a[rt] = *(const f16x8*)&HA[row * 256 + (((kb * 2 + (g >> 1)) ^ m) << 4) + (g & 1) * 8];
      }
#pragma unroll
      for (int ct = 0; ct < 2; ++ct)
        b[ct] = *(const f16x8*)&W3h[((size_t)(kb * 512 + qbase + wv * 32 + ct * 16 + m) << 5) + g * 8];
#pragma unroll
      for (int rt = 0; rt < 4; ++rt)
#pragma unroll
        for (int ct = 0; ct < 2; ++ct)
          accq[rt][ct] = __builtin_amdgcn_mfma_f32_16x16x32_f16(a[rt], b[ct], accq[rt][ct], 0, 0, 0);
    }
  };

  auto sw_write = [&](const f32x4 (&accq)[4][2]) {
#pragma unroll
    for (int rt = 0; rt < 4; ++rt)
#pragma unroll
      for (int r4 = 0; r4 < 4; ++r4) {
        int row = rt * 16 + g * 4 + r4;
        int rs = (row ^ (row >> 3)) & 7;
        f16x2 pk;
        pk[0] = (_Float16)accq[rt][0][r4];
        pk[1] = (_Float16)accq[rt][1][r4];
        int blk = ((wv * 2 + (m >> 3)) ^ rs) & 7;
        *(f16x2*)&SW[row * 128 + (blk << 4) + (m & 7) * 2] = pk;
      }
  };

  auto fold = [&](const _Float16* __restrict__ WLh, int qpart, f32x4 (&P)[4][2]) {
#pragma unroll
    for (int rt = 0; rt < 4; ++rt)
#pragma unroll
      for (int ct = 0; ct < 2; ++ct) P[rt][ct] = zero4;
#pragma unroll
    for (int kb = 0; kb < 4; ++kb) {
      f16x8 a[4], b[2];
#pragma unroll
      for (int rt = 0; rt < 4; ++rt) {
        int row = rt * 16 + m;
        int rs = (row ^ (row >> 3)) & 7;
        a[rt] = *(const f16x8*)&SP[row * 128 + ((((kb * 2 + (g >> 1)) ^ rs) & 7) << 4) + (g & 1) * 8];
      }
#pragma unroll
      for (int ct = 0; ct < 2; ++ct)
        b[ct] = *(const f16x8*)&WLh[((size_t)((qpart * 4 + kb) * 128 + wv * 32 + ct * 16 + m) << 5) + g * 8];
#pragma unroll
      for (int rt = 0; rt < 4; ++rt)
#pragma unroll
        for (int ct = 0; ct < 2; ++ct)
          P[rt][ct] = __builtin_amdgcn_mfma_f32_16x16x32_f16(a[rt], b[ct], P[rt][ct], 0, 0, 0);
    }
  };

  auto tp_xs = [&]() {
#pragma unroll
    for (int cch = 0; cch < 4; ++cch) {
      int ib = nw / 2 + cch * 8;
      int blk = ((ib >> 4) ^ ers) & 7;
      int off = e_loc * 128 + (blk << 4) + (ib & 15);
      f16x8 swv = *(const f16x8*)&SW[off];
      f16x8 upv = *(const f16x8*)&uprow[ib];
      f16x8 pr = swv * upv;
      *(f16x8*)&SP[off] = pr;
    }
  };

  _Float16 xvb[96];
  auto load_xv = [&]() {
#pragma unroll
    for (int u = 0; u < 12; ++u) {
      f16x8 t = *(const f16x8*)&uprow[128 + wv * 96 + u * 8];
#pragma unroll
      for (int z = 0; z < 8; ++z) xvb[u * 8 + z] = t[z];
    }
  };

  auto tp_w4 = [&]() {
    float4 ea = EAs[e_loc];
#pragma unroll
    for (int cch = 0; cch < 4; ++cch) {
      int ib = nw / 2 + cch * 8;
      int blk = ((ib >> 4) ^ ers) & 7;
      int off = e_loc * 128 + (blk << 4) + (ib & 15);
      f16x8 swv = *(const f16x8*)&SW[off];
      f16x8 outv;
#pragma unroll
      for (int z = 0; z < 8; ++z) {
        int k = cch * 8 + z;
        float d = (float)xvb[k * 3] * ea.y + (float)xvb[k * 3 + 1] * ea.z +
                  (float)xvb[k * 3 + 2] * ea.w;
        outv[z] = (_Float16)((float)swv[z] * d);
      }
      *(f16x8*)&SP[off] = outv;
    }
  };

  auto tp_w3 = [&](int c) {
#pragma unroll
    for (int cch = 0; cch < 4; ++cch) {
      int ib = nw / 2 + cch * 8;
      int blk = ((ib >> 4) ^ ers) & 7;
      int off = e_loc * 128 + (blk << 4) + (ib & 15);
      f16x8 swv = *(const f16x8*)&SW[off];
      f16x8 outv;
#pragma unroll
      for (int z = 0; z < 8; ++z) {
        int k = cch * 8 + z;
        outv[z] = swv[z] * xvb[k * 3 + c];
      }
      *(f16x8*)&SP[off] = outv;
    }
  };

  f32x4 accqA[4][2], accqB[4][2];
  f32x4 P1[4][2], P4[4][2], P2[4][2], P3[4][2];

  // q1 (w1): A1 = w1 (x) xs ; P1 = A1 @ WL0a. Queue q4 gemm before barrier.
  qgemm(0, accqA);
  sw_write(accqA);
  tp_xs();
  qgemm(384, accqB);          // w4, independent — fills the barrier wait
  __syncthreads();            // B1: SP(A1) complete
  fold(WL0h, 0, P1);
  sw_write(accqB);            // SW <- w4 (SW(w1) readers all pre-B1)
  load_xv();
  __syncthreads();            // B2: all folds done reading SP(A1)
  tp_w4();
  qgemm(128, accqA);          // w2 queued
  __syncthreads();            // B3: SP(A4) complete
  fold(WL0h, 1, P4);
  sw_write(accqA);            // SW <- w2 (tp_w4 reads all pre-B3)

  // scalar part: MIDs[:, j] = y0*P1 + P4/sqrt(3). Row = sender-sorted pos.
#pragma unroll
  for (int rt = 0; rt < 4; ++rt)
#pragma unroll
    for (int r4 = 0; r4 < 4; ++r4) {
      int row = rt * 16 + g * 4 + r4;
      float4 ea = EAs[row];
      f16x2 pk;
      pk[0] = (_Float16)(ea.x * P1[rt][0][r4] + INV_SQRT3F * P4[rt][0][r4]);
      pk[1] = (_Float16)(ea.x * P1[rt][1][r4] + INV_SQRT3F * P4[rt][1][r4]);
      *(f16x2*)&MIDs[(size_t)(e0 + row) * 512 + wv * 32 + m * 2] = pk;
    }
  __syncthreads();            // B4: folds done reading SP(A4)
  tp_xs();                    // SP <- A2 (reads SW(w2), own wave, pre-B4)
  qgemm(256, accqB);          // w3 queued
  __syncthreads();            // B5: SP(A2) complete
  fold(WL1h, 0, P2);
  sw_write(accqB);            // SW <- w3 (tp_xs reads all pre-B5)
  __syncthreads();            // B6: folds done reading SP(A2)

#pragma unroll
  for (int c = 0; c < 3; ++c) {
    tp_w3(c);                 // SP <- A3c (reads SW(w3), own wave)
    __syncthreads();          // SP complete
    fold(WL1h, 1, P3);
    // plane c: MIDs[:, 128 + c*128 + j] = yv[c]*P2 + y0*P3
#pragma unroll
    for (int rt = 0; rt < 4; ++rt)
#pragma unroll
      for (int r4 = 0; r4 < 4; ++r4) {
        int row = rt * 16 + g * 4 + r4;
        float4 ea = EAs[row];
        float yvc = (c == 0) ? ea.y : (c == 1) ? ea.z : ea.w;
        f16x2 pk;
        pk[0] = (_Float16)(yvc * P2[rt][0][r4] + ea.x * P3[rt][0][r4]);
        pk[1] = (_Float16)(yvc * P2[rt][1][r4] + ea.x * P3[rt][1][r4]);
        *(f16x2*)&MIDs[(size_t)(e0 + row) * 512 + 128 + c * 128 + wv * 32 + m * 2] = pk;
      }
    if (c < 2) __syncthreads();  // folds done reading SP before next tp_w3
  }
}

// ---------------------------------------------------------------------------
// Gather: one block per node; LDS-staged edge ids + 4-way unroll; output row
// staged in LDS and stored coalesced (float2/lane). EIDX holds sender-sorted
// positions => MIDs rows are contiguous per edge_mlp block.
// ---------------------------------------------------------------------------
__global__ __launch_bounds__(256) void gather_msg(
    const _Float16* __restrict__ MIDs, const int* __restrict__ OFF,
    const int* __restrict__ EIDX, float* __restrict__ out) {
  __shared__ int eb[256];
  __shared__ float os[512];
  const int n = blockIdx.x;
  const int t = threadIdx.x;
  const int beg = OFF[n], end = OFF[n + 1];
  float a0 = 0.f, a1 = 0.f;
  for (int base = beg; base < end; base += 256) {
    int cnt = min(256, end - base);
    __syncthreads();
    if (t < cnt) eb[t] = EIDX[base + t];
    __syncthreads();
    int k = 0;
    for (; k + 4 <= cnt; k += 4) {
      int e0_ = eb[k], e1_ = eb[k + 1], e2_ = eb[k + 2], e3_ = eb[k + 3];
      f16x2 v0 = *(const f16x2*)&MIDs[(size_t)e0_ * 512 + t * 2];
      f16x2 v1 = *(const f16x2*)&MIDs[(size_t)e1_ * 512 + t * 2];
      f16x2 v2 = *(const f16x2*)&MIDs[(size_t)e2_ * 512 + t * 2];
      f16x2 v3 = *(const f16x2*)&MIDs[(size_t)e3_ * 512 + t * 2];
      a0 += (float)v0[0] + (float)v1[0] + (float)v2[0] + (float)v3[0];
      a1 += (float)v0[1] + (float)v1[1] + (float)v2[1] + (float)v3[1];
    }
    for (; k < cnt; ++k) {
      f16x2 v = *(const f16x2*)&MIDs[(size_t)eb[k] * 512 + t * 2];
      a0 += (float)v[0];
      a1 += (float)v[1];
    }
  }
#pragma unroll
  for (int u = 0; u < 2; ++u) {
    int x = t * 2 + u;
    float a = u ? a1 : a0;
    int dst;
    if (x < 128) {
      dst = x * 4;
    } else {
      int xm = x - 128;
      int c = xm >> 7, j = xm & 127;
      dst = j * 4 + 1 + c;
    }
    os[dst] = a;
  }
  __syncthreads();
  *(float2*)&out[(size_t)n * 512 + t * 2] = *(const float2*)&os[t * 2];
}

// ---------------------------------------------------------------------------
extern "C" void kernel_launch(void* const* d_in, const int* in_sizes, int n_in,
                              void* d_out, int out_size, void* d_ws, size_t ws_size,
                              hipStream_t stream) {
  const float* node_feats = (const float*)d_in[1];
  const float* edge_attrs = (const float*)d_in[2];
  const float* edge_feats = (const float*)d_in[3];
  const int*   edge_index = (const int*)d_in[4];
  const float* W_up0   = (const float*)d_in[5];
  const float* W_up1   = (const float*)d_in[6];
  const float* W_down  = (const float*)d_in[7];
  const float* Wm0     = (const float*)d_in[8];
  const float* Wm1     = (const float*)d_in[9];
  const float* Wm2     = (const float*)d_in[10];
  const float* Wm3     = (const float*)d_in[11];
  const float* W_lin0  = (const float*)d_in[12];
  const float* W_lin1  = (const float*)d_in[13];
  const float* W_skip0 = (const float*)d_in[14];
  const float* W_skip1 = (const float*)d_in[15];
  float* out = (float*)d_out;

  char* ws = (char*)d_ws;
  size_t off = 0;
  auto alloc = [&](size_t bytes) {
    void* p = ws + off;
    off = (off + bytes + 255) & ~(size_t)255;
    return p;
  };
  _Float16* UPH   = (_Float16*)alloc((size_t)NN * 512 * 2);
  _Float16* DOWNH = (_Float16*)alloc((size_t)NN * 64 * 2);
  _Float16* W0h   = (_Float16*)alloc(160 * 256 * 2);
  _Float16* W1h   = (_Float16*)alloc(256 * 256 * 2);
  _Float16* W2h   = (_Float16*)alloc(256 * 256 * 2);
  _Float16* W3h   = (_Float16*)alloc(256 * 512 * 2);
  _Float16* WL0h  = (_Float16*)alloc(256 * 128 * 2);
  _Float16* WL1h  = (_Float16*)alloc(256 * 128 * 2);
  _Float16* WS0h  = (_Float16*)alloc(128 * 256 * 2);  // [Wup0|Wskip0]
  _Float16* WS1h  = (_Float16*)alloc(128 * 256 * 2);  // [Wup1|Wskip1]
  _Float16* WDh   = (_Float16*)alloc(128 * 64 * 2);   // Wdown
  int*      CNTS  = (int*)alloc((size_t)2 * NN * 4);  // CNT | CNT2, one memset
  int*      CNT   = CNTS;
  int*      CNT2  = CNTS + NN;
  int*      OFF   = (int*)alloc((size_t)(NN + 1) * 4);
  int*      CUR   = (int*)alloc((size_t)NN * 4);
  int*      EIDX  = (int*)alloc((size_t)NE * 4);
  int*      OFF2  = (int*)alloc((size_t)(NN + 1) * 4);
  int*      CUR2  = (int*)alloc((size_t)NN * 4);
  int*      SIDX  = (int*)alloc((size_t)NE * 4);
  _Float16* MIDs  = (_Float16*)alloc((size_t)NE * 512 * 2);

  hipMemsetAsync(CNTS, 0, (size_t)2 * NN * 4, stream);

  // wconv9 = 9 weight conversions (1056 blocks) + edge counting (625).
  wconv9<<<1681, 256, 0, stream>>>(Wm0, Wm1, Wm2, Wm3, W_lin0, W_lin1,
                                   W0h, W1h, W2h, W3h, WL0h, WL1h,
                                   W_up0, W_skip0, W_up1, W_skip1, W_down,
                                   WS0h, WS1h, WDh,
                                   edge_index, CNT, CNT2);

  // node pre-pass as MFMA GEMMs (157 s-blocks + 469 v-blocks)
  prep2<<<626, 256, 0, stream>>>(node_feats, WS0h, WS1h, WDh,
                                 UPH, DOWNH, out + (size_t)NN * 512);

  k_scan2<<<2, 1024, 0, stream>>>(CNT, OFF, CUR, CNT2, OFF2, CUR2);
  k_fill2<<<625, 256, 0, stream>>>(edge_index, CUR, EIDX, CUR2, SIDX);

  edge_mlp<<<2500, 256, 0, stream>>>(edge_attrs, edge_feats, edge_index, SIDX,
                                     DOWNH, UPH, W0h, W1h, W2h, W3h, WL0h, WL1h,
                                     MIDs);
  gather_msg<<<NN, 256, 0, stream>>>(MIDs, OFF, EIDX, out);
}

// Round 9
// 430.257 us; speedup vs baseline: 1.3810x; 1.0307x over previous
//
#include <hip/hip_runtime.h>
#include <cmath>

#define NN 10000
#define NE 160000
#define INV_SQRT_C 0.08838834764831845f   // 1/sqrt(128)
#define INV_SQRT3F 0.5773502691896258f

typedef _Float16 f16x8 __attribute__((ext_vector_type(8)));
typedef _Float16 f16x4 __attribute__((ext_vector_type(4)));
typedef _Float16 f16x2 __attribute__((ext_vector_type(2)));
typedef float    f32x4 __attribute__((ext_vector_type(4)));

__device__ __forceinline__ float silu_f(float x) {
  return x / (1.f + __expf(-x));
}

// ---------------------------------------------------------------------------
// wconv9: all weight conversions (9 jobs) + edge-endpoint counting in ONE
// launch. Node GEMMs live in prep2 (they read WS0h/WS1h/WDh — no intra-grid
// ordering). B-fragment layout: storage slot ct*16+m within a P-chunk holds
// logical col m*(P/16)+ct.
// ---------------------------------------------------------------------------
__device__ __forceinline__ void wconv_one(
    int bx, const float* __restrict__ src, _Float16* __restrict__ dst,
    int Korig, int Kpad, int N, float scale, int P) {
  int total = Kpad * N;
  for (int t = bx * 256 + threadIdx.x; t < total; t += 128 * 256) {
    int n = t % N;
    int k = t / N;
    int kb = k >> 5, kk = k & 31;
    int sub = n & (P - 1);
    int n_l = (n & ~(P - 1)) | ((sub & 15) * (P >> 4) + (sub >> 4));
    float v = (k < Korig) ? src[(size_t)k * N + n_l] * scale : 0.f;
    dst[((size_t)(kb * N + n) << 5) + kk] = (_Float16)v;
  }
}

// [A | B] side-by-side as K=128 x N=256, P=64 (chunks never cross col 128)
__device__ __forceinline__ void wconv_pair(
    int bx, const float* __restrict__ A, const float* __restrict__ B,
    _Float16* __restrict__ dst, float scale) {
  int tgl = bx * 256 + threadIdx.x;          // 0..32767, exactly one elem
  int n = tgl & 255;
  int k = tgl >> 8;
  int kb = k >> 5, kk = k & 31;
  int sub = n & 63;
  int n_l = (n & ~63) | ((sub & 15) * 4 + (sub >> 4));
  float v = ((n_l < 128) ? A[(size_t)k * 128 + n_l]
                         : B[(size_t)k * 128 + (n_l - 128)]) * scale;
  dst[((size_t)(kb * 256 + n) << 5) + kk] = (_Float16)v;
}

// W_down: K=128 x N=64, P=16 (identity permutation)
__device__ __forceinline__ void wconv_dn(
    int bx, const float* __restrict__ src, _Float16* __restrict__ dst,
    float scale) {
  int tgl = bx * 256 + threadIdx.x;          // 0..8191, exactly one elem
  int n = tgl & 63;
  int k = tgl >> 6;
  int kb = k >> 5, kk = k & 31;
  float v = src[(size_t)k * 64 + n] * scale;
  dst[((size_t)(kb * 64 + n) << 5) + kk] = (_Float16)v;
}

__global__ __launch_bounds__(256) void wconv9(
    const float* __restrict__ s0, const float* __restrict__ s1,
    const float* __restrict__ s2, const float* __restrict__ s3,
    const float* __restrict__ s4, const float* __restrict__ s5,
    _Float16* __restrict__ d0, _Float16* __restrict__ d1,
    _Float16* __restrict__ d2, _Float16* __restrict__ d3,
    _Float16* __restrict__ d4, _Float16* __restrict__ d5,
    const float* __restrict__ W_up0, const float* __restrict__ W_skip0,
    const float* __restrict__ W_up1, const float* __restrict__ W_skip1,
    const float* __restrict__ W_down,
    _Float16* __restrict__ WS0h, _Float16* __restrict__ WS1h,
    _Float16* __restrict__ WDh,
    const int* __restrict__ edge_index,
    int* __restrict__ CNT, int* __restrict__ CNT2) {
  const int b = blockIdx.x;
  if (b < 768) {
    const int job = b >> 7, bx = b & 127;
    switch (job) {
      case 0: wconv_one(bx, s0, d0, 136, 160, 256, 0.08574929257125442f, 64); break;
      case 1: wconv_one(bx, s1, d1, 256, 256, 256, 0.0625f, 64); break;
      case 2: wconv_one(bx, s2, d2, 256, 256, 256, 0.0625f, 64); break;
      case 3: wconv_one(bx, s3, d3, 256, 256, 512, 0.0625f, 32); break;
      case 4: wconv_one(bx, s4, d4, 256, 256, 128, 1.0f / 256.0f, 32); break;
      default: wconv_one(bx, s5, d5, 256, 256, 128, 1.0f / 256.0f, 32); break;
    }
  } else if (b < 896) {
    wconv_pair(b - 768, W_up0, W_skip0, WS0h, INV_SQRT_C);
  } else if (b < 1024) {
    wconv_pair(b - 896, W_up1, W_skip1, WS1h, INV_SQRT_C);
  } else if (b < 1056) {
    wconv_dn(b - 1024, W_down, WDh, INV_SQRT_C);
  } else {
    int e = (b - 1056) * 256 + threadIdx.x;   // 625*256 = NE exactly
    if (e < NE) {
      int2 sr = *(const int2*)&edge_index[(size_t)e * 2];
      atomicAdd(&CNT[sr.y], 1);    // receiver
      atomicAdd(&CNT2[sr.x], 1);   // sender
    }
  }
}

// ---------------------------------------------------------------------------
// prep2: node pre-pass as MFMA GEMMs. Fragment conventions identical to
// edge_mlp's verified layers. A-tile XOR-swizzled in LDS.
// ---------------------------------------------------------------------------
__global__ __launch_bounds__(256) void prep2(
    const float* __restrict__ feats,
    const _Float16* __restrict__ WS0h, const _Float16* __restrict__ WS1h,
    const _Float16* __restrict__ WDh,
    _Float16* __restrict__ UPH, _Float16* __restrict__ DOWNH,
    float* __restrict__ out_sc) {
  __shared__ _Float16 As[64 * 128];   // 16 KB
  const int b = blockIdx.x;
  const int t = threadIdx.x;
  const int lane = t & 63;
  const int wv = t >> 6;
  const int m = lane & 15;
  const int g = lane >> 4;
  f32x4 zero4 = {0.f, 0.f, 0.f, 0.f};
  f16x8 zf = {0, 0, 0, 0, 0, 0, 0, 0};

  if (b < 157) {
    // ---------------- s-part: nodes n0..n0+63
    const int n0 = b * 64;
    for (int idx = t; idx < 1024; idx += 256) {
      int r = idx >> 4, c8 = idx & 15;     // 8-elem k-chunk
      int n = n0 + r;
      f16x8 av = zf;
      if (n < NN) {
        const float* src = &feats[(size_t)n * 512 + c8 * 8];
        float4 f0 = *(const float4*)src;
        float4 f1 = *(const float4*)(src + 4);
        av[0] = (_Float16)f0.x; av[1] = (_Float16)f0.y;
        av[2] = (_Float16)f0.z; av[3] = (_Float16)f0.w;
        av[4] = (_Float16)f1.x; av[5] = (_Float16)f1.y;
        av[6] = (_Float16)f1.z; av[7] = (_Float16)f1.w;
      }
      int sb = (c8 >> 1) ^ (r & 7);
      *(f16x8*)&As[r * 128 + (sb << 4) + (c8 & 1) * 8] = av;
    }
    __syncthreads();

    f32x4 acc[4][4];
    f32x4 acc2[4];
#pragma unroll
    for (int rt = 0; rt < 4; ++rt) {
      acc2[rt] = zero4;
#pragma unroll
      for (int ct = 0; ct < 4; ++ct) acc[rt][ct] = zero4;
    }
#pragma unroll
    for (int kb = 0; kb < 4; ++kb) {
      f16x8 a[4], bf[4];
#pragma unroll
      for (int rt = 0; rt < 4; ++rt) {
        int row = rt * 16 + m;
        a[rt] = *(const f16x8*)&As[row * 128 +
                 ((((kb * 2 + (g >> 1)) ^ (m & 7)) & 7) << 4) + (g & 1) * 8];
      }
#pragma unroll
      for (int ct = 0; ct < 4; ++ct)
        bf[ct] = *(const f16x8*)&WS0h[((size_t)(kb * 256 + wv * 64 + ct * 16 + m) << 5) + g * 8];
      f16x8 bd = *(const f16x8*)&WDh[((size_t)(kb * 64 + wv * 16 + m) << 5) + g * 8];
#pragma unroll
      for (int rt = 0; rt < 4; ++rt) {
#pragma unroll
        for (int ct = 0; ct < 4; ++ct)
          acc[rt][ct] = __builtin_amdgcn_mfma_f32_16x16x32_f16(a[rt], bf[ct], acc[rt][ct], 0, 0, 0);
        acc2[rt] = __builtin_amdgcn_mfma_f32_16x16x32_f16(a[rt], bd, acc2[rt], 0, 0, 0);
      }
    }
#pragma unroll
    for (int rt = 0; rt < 4; ++rt)
#pragma unroll
      for (int q = 0; q < 4; ++q) {
        int row = rt * 16 + g * 4 + q;
        int n = n0 + row;
        if (n >= NN) continue;
        if (wv < 2) {
          f16x4 pk;
#pragma unroll
          for (int ct = 0; ct < 4; ++ct) pk[ct] = (_Float16)acc[rt][ct][q];
          *(f16x4*)&UPH[(size_t)n * 512 + wv * 64 + m * 4] = pk;
        } else {
          float4 p4 = {acc[rt][0][q], acc[rt][1][q], acc[rt][2][q], acc[rt][3][q]};
          *(float4*)&out_sc[(size_t)n * 512 + (wv - 2) * 64 + m * 4] = p4;
        }
        DOWNH[(size_t)n * 64 + wv * 16 + m] = (_Float16)acc2[rt][q];
      }
  } else if (b < 626) {
    // ---------------- v-part: rows are (n,c) pairs, rg = n*3+c
    const int v0 = (b - 157) * 64;
    for (int idx = t; idx < 1024; idx += 256) {
      int r = idx >> 4, c8 = idx & 15;
      int rg = v0 + r;
      f16x8 av = zf;
      if (rg < 3 * NN) {
        int n = rg / 3, c = rg - n * 3;
        const float* src = &feats[(size_t)n * 512 + 128 + c];
#pragma unroll
        for (int z = 0; z < 8; ++z) av[z] = (_Float16)src[(c8 * 8 + z) * 3];
      }
      int sb = (c8 >> 1) ^ (r & 7);
      *(f16x8*)&As[r * 128 + (sb << 4) + (c8 & 1) * 8] = av;
    }
    __syncthreads();

    f32x4 acc[4][4];
#pragma unroll
    for (int rt = 0; rt < 4; ++rt)
#pragma unroll
      for (int ct = 0; ct < 4; ++ct) acc[rt][ct] = zero4;
#pragma unroll
    for (int kb = 0; kb < 4; ++kb) {
      f16x8 a[4], bf[4];
#pragma unroll
      for (int rt = 0; rt < 4; ++rt) {
        int row = rt * 16 + m;
        a[rt] = *(const f16x8*)&As[row * 128 +
                 ((((kb * 2 + (g >> 1)) ^ (m & 7)) & 7) << 4) + (g & 1) * 8];
      }
#pragma unroll
      for (int ct = 0; ct < 4; ++ct)
        bf[ct] = *(const f16x8*)&WS1h[((size_t)(kb * 256 + wv * 64 + ct * 16 + m) << 5) + g * 8];
#pragma unroll
      for (int rt = 0; rt < 4; ++rt)
#pragma unroll
        for (int ct = 0; ct < 4; ++ct)
          acc[rt][ct] = __builtin_amdgcn_mfma_f32_16x16x32_f16(a[rt], bf[ct], acc[rt][ct], 0, 0, 0);
    }
#pragma unroll
    for (int rt = 0; rt < 4; ++rt)
#pragma unroll
      for (int q = 0; q < 4; ++q) {
        int row = rt * 16 + g * 4 + q;
        int rg = v0 + row;
        if (rg >= 3 * NN) continue;
        int n = rg / 3, c = rg - (rg / 3) * 3;
        if (wv < 2) {
#pragma unroll
          for (int ct = 0; ct < 4; ++ct) {
            int j = wv * 64 + m * 4 + ct;
            UPH[(size_t)n * 512 + 128 + j * 3 + c] = (_Float16)acc[rt][ct][q];
          }
        } else {
#pragma unroll
          for (int ct = 0; ct < 4; ++ct) {
            int j = (wv - 2) * 64 + m * 4 + ct;
            out_sc[(size_t)n * 512 + 128 + j * 3 + c] = acc[rt][ct][q];
          }
        }
      }
  }
}

// ---------------------------------------------------------------------------
// CSR scan + fill (verbatim round 4).
// ---------------------------------------------------------------------------
__device__ __forceinline__ void scan_one(const int* __restrict__ CNT,
                                         int* __restrict__ OFF,
                                         int* __restrict__ CUR, int* ts) {
  const int t = threadIdx.x;
  const int base = t * 10;
  int loc[10];
  int s = 0;
#pragma unroll
  for (int i = 0; i < 10; ++i) {
    int idx = base + i;
    int v = (idx < NN) ? CNT[idx] : 0;
    loc[i] = s;
    s += v;
  }
  ts[t] = s;
  __syncthreads();
  for (int off = 1; off < 1024; off <<= 1) {
    int v = (t >= off) ? ts[t - off] : 0;
    __syncthreads();
    ts[t] += v;
    __syncthreads();
  }
  int tp = (t > 0) ? ts[t - 1] : 0;
#pragma unroll
  for (int i = 0; i < 10; ++i) {
    int idx = base + i;
    if (idx < NN) {
      OFF[idx] = tp + loc[i];
      CUR[idx] = tp + loc[i];
    }
  }
  if (t == 1023) OFF[NN] = ts[1023];
}

__global__ __launch_bounds__(1024) void k_scan2(
    const int* __restrict__ CNT, int* __restrict__ OFF, int* __restrict__ CUR,
    const int* __restrict__ CNT2, int* __restrict__ OFF2, int* __restrict__ CUR2) {
  __shared__ int ts[1024];
  if (blockIdx.x == 0) scan_one(CNT, OFF, CUR, ts);
  else                 scan_one(CNT2, OFF2, CUR2, ts);
}

__global__ void k_fill2(const int* __restrict__ edge_index,
                        int* __restrict__ CUR, int* __restrict__ EIDX,
                        int* __restrict__ CUR2, int* __restrict__ SIDX) {
  int e = blockIdx.x * blockDim.x + threadIdx.x;
  if (e < NE) {
    int2 sr = *(const int2*)&edge_index[(size_t)e * 2];
    int ps = atomicAdd(&CUR2[sr.x], 1);  // sender-sorted position
    SIDX[ps] = e;
    int pr = atomicAdd(&CUR[sr.y], 1);   // receiver-CSR slot
    EIDX[pr] = ps;                       // gather reads MIDs[ps]
  }
}

// ---------------------------------------------------------------------------
// Fused edge kernel — round-0 verified structure; VERBATIM from round 8
// (device code unchanged this round — the experiment variable is the
// WORKSPACE LAYOUT only, restoring round-4/6 byte offsets for all buffers
// edge_mlp touches; WS0h/WS1h/WDh moved to the end of the workspace).
// ---------------------------------------------------------------------------
__device__ __forceinline__ void mlp_layer_256(
    const _Float16* In, _Float16* Out, const _Float16* __restrict__ Wz,
    int m, int g, int wv) {
  f32x4 acc[4][4];
  f32x4 zero4 = {0.f, 0.f, 0.f, 0.f};
#pragma unroll
  for (int rt = 0; rt < 4; ++rt)
#pragma unroll
    for (int ct = 0; ct < 4; ++ct) acc[rt][ct] = zero4;

#pragma unroll
  for (int kb = 0; kb < 8; ++kb) {
    f16x8 a[4], b[4];
#pragma unroll
    for (int rt = 0; rt < 4; ++rt) {
      int row = rt * 16 + m;
      a[rt] = *(const f16x8*)&In[row * 256 + (((kb * 2 + (g >> 1)) ^ m) << 4) + (g & 1) * 8];
    }
#pragma unroll
    for (int ct = 0; ct < 4; ++ct)
      b[ct] = *(const f16x8*)&Wz[((size_t)(kb * 256 + wv * 64 + ct * 16 + m) << 5) + g * 8];
#pragma unroll
    for (int rt = 0; rt < 4; ++rt)
#pragma unroll
      for (int ct = 0; ct < 4; ++ct)
        acc[rt][ct] = __builtin_amdgcn_mfma_f32_16x16x32_f16(a[rt], b[ct], acc[rt][ct], 0, 0, 0);
  }
#pragma unroll
  for (int rt = 0; rt < 4; ++rt)
#pragma unroll
    for (int q = 0; q < 4; ++q) {
      int row = rt * 16 + g * 4 + q;
      f16x4 pk;
#pragma unroll
      for (int ct = 0; ct < 4; ++ct) pk[ct] = (_Float16)silu_f(acc[rt][ct][q]);
      int blk = (wv * 4 + (m >> 2)) ^ (row & 15);
      *(f16x4*)&Out[row * 256 + (blk << 4) + (m & 3) * 4] = pk;
    }
}

__global__ __launch_bounds__(256, 2) void edge_mlp(
    const float* __restrict__ edge_attrs,
    const float* __restrict__ edge_feats,
    const int* __restrict__ edge_index,
    const int* __restrict__ SIDX,
    const _Float16* __restrict__ DOWNH,
    const _Float16* __restrict__ UPH,
    const _Float16* __restrict__ W0h, const _Float16* __restrict__ W1h,
    const _Float16* __restrict__ W2h, const _Float16* __restrict__ W3h,
    const _Float16* __restrict__ WL0h, const _Float16* __restrict__ WL1h,
    _Float16* __restrict__ MIDs) {
  __shared__ _Float16 HA[64 * 256];
  __shared__ _Float16 HB[64 * 256];
  __shared__ int    SNDs[64];
  __shared__ float4 EAs[64];

  const int tid = threadIdx.x;
  const int lane = tid & 63;
  const int wv = tid >> 6;
  const int m = lane & 15;
  const int g = lane >> 4;
  const int e0 = blockIdx.x * 64;
  const int nw = wv * 64;

  // stage epilogue metadata (visible after the first barrier)
  if (tid < 64) {
    int el = SIDX[e0 + tid];
    SNDs[tid] = edge_index[(size_t)el * 2];
    EAs[tid] = *(const float4*)&edge_attrs[(size_t)el * 4];
  }

  int el_r[4], snd_r[4], rcv_r[4];
#pragma unroll
  for (int rt = 0; rt < 4; ++rt) {
    el_r[rt] = SIDX[e0 + rt * 16 + m];
    int2 sr = *(const int2*)&edge_index[(size_t)el_r[rt] * 2];
    snd_r[rt] = sr.x;
    rcv_r[rt] = sr.y;
  }

  f32x4 zero4 = {0.f, 0.f, 0.f, 0.f};
  f16x8 zf = {0, 0, 0, 0, 0, 0, 0, 0};

  // ---------------- layer 0: aug(136, padded 160) -> h1 (HA)
  {
    f32x4 acc[4][4];
#pragma unroll
    for (int rt = 0; rt < 4; ++rt)
#pragma unroll
      for (int ct = 0; ct < 4; ++ct) acc[rt][ct] = zero4;

#pragma unroll
    for (int kb = 0; kb < 5; ++kb) {
      const int k0 = kb * 32 + g * 8;
      f16x8 a[4], b[4];
#pragma unroll
      for (int rt = 0; rt < 4; ++rt) {
        if (k0 == 0) {
          const float* ef = &edge_feats[(size_t)el_r[rt] * 8];
          float4 f0 = *(const float4*)ef;
          float4 f1 = *(const float4*)(ef + 4);
          f16x8 av;
          av[0] = (_Float16)f0.x; av[1] = (_Float16)f0.y;
          av[2] = (_Float16)f0.z; av[3] = (_Float16)f0.w;
          av[4] = (_Float16)f1.x; av[5] = (_Float16)f1.y;
          av[6] = (_Float16)f1.z; av[7] = (_Float16)f1.w;
          a[rt] = av;
        } else if (k0 < 72) {
          a[rt] = *(const f16x8*)&DOWNH[(size_t)snd_r[rt] * 64 + (k0 - 8)];
        } else if (k0 < 136) {
          a[rt] = *(const f16x8*)&DOWNH[(size_t)rcv_r[rt] * 64 + (k0 - 72)];
        } else {
          a[rt] = zf;
        }
      }
#pragma unroll
      for (int ct = 0; ct < 4; ++ct)
        b[ct] = *(const f16x8*)&W0h[((size_t)(kb * 256 + nw + ct * 16 + m) << 5) + g * 8];
#pragma unroll
      for (int rt = 0; rt < 4; ++rt)
#pragma unroll
        for (int ct = 0; ct < 4; ++ct)
          acc[rt][ct] = __builtin_amdgcn_mfma_f32_16x16x32_f16(a[rt], b[ct], acc[rt][ct], 0, 0, 0);
    }
#pragma unroll
    for (int rt = 0; rt < 4; ++rt)
#pragma unroll
      for (int q = 0; q < 4; ++q) {
        int row = rt * 16 + g * 4 + q;
        f16x4 pk;
#pragma unroll
        for (int ct = 0; ct < 4; ++ct) pk[ct] = (_Float16)silu_f(acc[rt][ct][q]);
        int blk = (wv * 4 + (m >> 2)) ^ (row & 15);
        *(f16x4*)&HA[row * 256 + (blk << 4) + (m & 3) * 4] = pk;
      }
  }
  __syncthreads();

  mlp_layer_256(HA, HB, W1h, m, g, wv);   // layer 1: h1 -> h2
  __syncthreads();
  mlp_layer_256(HB, HA, W2h, m, g, wv);   // layer 2: h2 -> h3 (HA stays live)
  __syncthreads();

  // ================= epilogue =================
  _Float16* SW = HB;             // 64 x 128 fp16, tpw quarter
  _Float16* SP = HB + 64 * 128;  // 64 x 128 fp16, TP'd A-matrix

  const int e_loc = lane;
  const int ers = (e_loc ^ (e_loc >> 3)) & 7;
  const int snd_e = SNDs[e_loc];
  const _Float16* uprow = &UPH[(size_t)snd_e * 512];

  // quarter GEMM into caller-provided acc buffer
  auto qgemm = [&](int qbase, f32x4 (&accq)[4][2]) {
#pragma unroll
    for (int rt = 0; rt < 4; ++rt)
#pragma unroll
      for (int ct = 0; ct < 2; ++ct) accq[rt][ct] = zero4;
#pragma unroll
    for (int kb = 0; kb < 8; ++kb) {
      f16x8 a[4], b[2];
#pragma unroll
      for (int rt = 0; rt < 4; ++rt) {
        int row = rt * 16 + m;
        a[rt] = *(const f16x8*)&HA[row * 256 + (((kb * 2 + (g >> 1)) ^ m) << 4) + (g & 1) * 8];
      }
#pragma unroll
      for (int ct = 0; ct < 2; ++ct)
        b[ct] = *(const f16x8*)&W3h[((size_t)(kb * 512 + qbase + wv * 32 + ct * 16 + m) << 5) + g * 8];
#pragma unroll
      for (int rt = 0; rt < 4; ++rt)
#pragma unroll
        for (int ct = 0; ct < 2; ++ct)
          accq[rt][ct] = __builtin_amdgcn_mfma_f32_16x16x32_f16(a[rt], b[ct], accq[rt][ct], 0, 0, 0);
    }
  };

  auto sw_write = [&](const f32x4 (&accq)[4][2]) {
#pragma unroll
    for (int rt = 0; rt < 4; ++rt)
#pragma unroll
      for (int r4 = 0; r4 < 4; ++r4) {
        int row = rt * 16 + g * 4 + r4;
        int rs = (row ^ (row >> 3)) & 7;
        f16x2 pk;
        pk[0] = (_Float16)accq[rt][0][r4];
        pk[1] = (_Float16)accq[rt][1][r4];
        int blk = ((wv * 2 + (m >> 3)) ^ rs) & 7;
        *(f16x2*)&SW[row * 128 + (blk << 4) + (m & 7) * 2] = pk;
      }
  };

  auto fold = [&](const _Float16* __restrict__ WLh, int qpart, f32x4 (&P)[4][2]) {
#pragma unroll
    for (int rt = 0; rt < 4; ++rt)
#pragma unroll
      for (int ct = 0; ct < 2; ++ct) P[rt][ct] = zero4;
#pragma unroll
    for (int kb = 0; kb < 4; ++kb) {
      f16x8 a[4], b[2];
#pragma unroll
      for (int rt = 0; rt < 4; ++rt) {
        int row = rt * 16 + m;
        int rs = (row ^ (row >> 3)) & 7;
        a[rt] = *(const f16x8*)&SP[row * 128 + ((((kb * 2 + (g >> 1)) ^ rs) & 7) << 4) + (g & 1) * 8];
      }
#pragma unroll
      for (int ct = 0; ct < 2; ++ct)
        b[ct] = *(const f16x8*)&WLh[((size_t)((qpart * 4 + kb) * 128 + wv * 32 + ct * 16 + m) << 5) + g * 8];
#pragma unroll
      for (int rt = 0; rt < 4; ++rt)
#pragma unroll
        for (int ct = 0; ct < 2; ++ct)
          P[rt][ct] = __builtin_amdgcn_mfma_f32_16x16x32_f16(a[rt], b[ct], P[rt][ct], 0, 0, 0);
    }
  };

  auto tp_xs = [&]() {
#pragma unroll
    for (int cch = 0; cch < 4; ++cch) {
      int ib = nw / 2 + cch * 8;
      int blk = ((ib >> 4) ^ ers) & 7;
      int off = e_loc * 128 + (blk << 4) + (ib & 15);
      f16x8 swv = *(const f16x8*)&SW[off];
      f16x8 upv = *(const f16x8*)&uprow[ib];
      f16x8 pr = swv * upv;
      *(f16x8*)&SP[off] = pr;
    }
  };

  _Float16 xvb[96];
  auto load_xv = [&]() {
#pragma unroll
    for (int u = 0; u < 12; ++u) {
      f16x8 t = *(const f16x8*)&uprow[128 + wv * 96 + u * 8];
#pragma unroll
      for (int z = 0; z < 8; ++z) xvb[u * 8 + z] = t[z];
    }
  };

  auto tp_w4 = [&]() {
    float4 ea = EAs[e_loc];
#pragma unroll
    for (int cch = 0; cch < 4; ++cch) {
      int ib = nw / 2 + cch * 8;
      int blk = ((ib >> 4) ^ ers) & 7;
      int off = e_loc * 128 + (blk << 4) + (ib & 15);
      f16x8 swv = *(const f16x8*)&SW[off];
      f16x8 outv;
#pragma unroll
      for (int z = 0; z < 8; ++z) {
        int k = cch * 8 + z;
        float d = (float)xvb[k * 3] * ea.y + (float)xvb[k * 3 + 1] * ea.z +
                  (float)xvb[k * 3 + 2] * ea.w;
        outv[z] = (_Float16)((float)swv[z] * d);
      }
      *(f16x8*)&SP[off] = outv;
    }
  };

  auto tp_w3 = [&](int c) {
#pragma unroll
    for (int cch = 0; cch < 4; ++cch) {
      int ib = nw / 2 + cch * 8;
      int blk = ((ib >> 4) ^ ers) & 7;
      int off = e_loc * 128 + (blk << 4) + (ib & 15);
      f16x8 swv = *(const f16x8*)&SW[off];
      f16x8 outv;
#pragma unroll
      for (int z = 0; z < 8; ++z) {
        int k = cch * 8 + z;
        outv[z] = swv[z] * xvb[k * 3 + c];
      }
      *(f16x8*)&SP[off] = outv;
    }
  };

  f32x4 accqA[4][2], accqB[4][2];
  f32x4 P1[4][2], P4[4][2], P2[4][2], P3[4][2];

  // q1 (w1): A1 = w1 (x) xs ; P1 = A1 @ WL0a. Queue q4 gemm before barrier.
  qgemm(0, accqA);
  sw_write(accqA);
  tp_xs();
  qgemm(384, accqB);          // w4, independent — fills the barrier wait
  __syncthreads();            // B1: SP(A1) complete
  fold(WL0h, 0, P1);
  sw_write(accqB);            // SW <- w4 (SW(w1) readers all pre-B1)
  load_xv();
  __syncthreads();            // B2: all folds done reading SP(A1)
  tp_w4();
  qgemm(128, accqA);          // w2 queued
  __syncthreads();            // B3: SP(A4) complete
  fold(WL0h, 1, P4);
  sw_write(accqA);            // SW <- w2 (tp_w4 reads all pre-B3)

  // scalar part: MIDs[:, j] = y0*P1 + P4/sqrt(3). Row = sender-sorted pos.
#pragma unroll
  for (int rt = 0; rt < 4; ++rt)
#pragma unroll
    for (int r4 = 0; r4 < 4; ++r4) {
      int row = rt * 16 + g * 4 + r4;
      float4 ea = EAs[row];
      f16x2 pk;
      pk[0] = (_Float16)(ea.x * P1[rt][0][r4] + INV_SQRT3F * P4[rt][0][r4]);
      pk[1] = (_Float16)(ea.x * P1[rt][1][r4] + INV_SQRT3F * P4[rt][1][r4]);
      *(f16x2*)&MIDs[(size_t)(e0 + row) * 512 + wv * 32 + m * 2] = pk;
    }
  __syncthreads();            // B4: folds done reading SP(A4)
  tp_xs();                    // SP <- A2 (reads SW(w2), own wave, pre-B4)
  qgemm(256, accqB);          // w3 queued
  __syncthreads();            // B5: SP(A2) complete
  fold(WL1h, 0, P2);
  sw_write(accqB);            // SW <- w3 (tp_xs reads all pre-B5)
  __syncthreads();            // B6: folds done reading SP(A2)

#pragma unroll
  for (int c = 0; c < 3; ++c) {
    tp_w3(c);                 // SP <- A3c (reads SW(w3), own wave)
    __syncthreads();          // SP complete
    fold(WL1h, 1, P3);
    // plane c: MIDs[:, 128 + c*128 + j] = yv[c]*P2 + y0*P3
#pragma unroll
    for (int rt = 0; rt < 4; ++rt)
#pragma unroll
      for (int r4 = 0; r4 < 4; ++r4) {
        int row = rt * 16 + g * 4 + r4;
        float4 ea = EAs[row];
        float yvc = (c == 0) ? ea.y : (c == 1) ? ea.z : ea.w;
        f16x2 pk;
        pk[0] = (_Float16)(yvc * P2[rt][0][r4] + ea.x * P3[rt][0][r4]);
        pk[1] = (_Float16)(yvc * P2[rt][1][r4] + ea.x * P3[rt][1][r4]);
        *(f16x2*)&MIDs[(size_t)(e0 + row) * 512 + 128 + c * 128 + wv * 32 + m * 2] = pk;
      }
    if (c < 2) __syncthreads();  // folds done reading SP before next tp_w3
  }
}

// ---------------------------------------------------------------------------
// Gather: one block per node; LDS-staged edge ids + 4-way unroll; output row
// staged in LDS and stored coalesced (float2/lane). EIDX holds sender-sorted
// positions => MIDs rows are contiguous per edge_mlp block.
// ---------------------------------------------------------------------------
__global__ __launch_bounds__(256) void gather_msg(
    const _Float16* __restrict__ MIDs, const int* __restrict__ OFF,
    const int* __restrict__ EIDX, float* __restrict__ out) {
  __shared__ int eb[256];
  __shared__ float os[512];
  const int n = blockIdx.x;
  const int t = threadIdx.x;
  const int beg = OFF[n], end = OFF[n + 1];
  float a0 = 0.f, a1 = 0.f;
  for (int base = beg; base < end; base += 256) {
    int cnt = min(256, end - base);
    __syncthreads();
    if (t < cnt) eb[t] = EIDX[base + t];
    __syncthreads();
    int k = 0;
    for (; k + 4 <= cnt; k += 4) {
      int e0_ = eb[k], e1_ = eb[k + 1], e2_ = eb[k + 2], e3_ = eb[k + 3];
      f16x2 v0 = *(const f16x2*)&MIDs[(size_t)e0_ * 512 + t * 2];
      f16x2 v1 = *(const f16x2*)&MIDs[(size_t)e1_ * 512 + t * 2];
      f16x2 v2 = *(const f16x2*)&MIDs[(size_t)e2_ * 512 + t * 2];
      f16x2 v3 = *(const f16x2*)&MIDs[(size_t)e3_ * 512 + t * 2];
      a0 += (float)v0[0] + (float)v1[0] + (float)v2[0] + (float)v3[0];
      a1 += (float)v0[1] + (float)v1[1] + (float)v2[1] + (float)v3[1];
    }
    for (; k < cnt; ++k) {
      f16x2 v = *(const f16x2*)&MIDs[(size_t)eb[k] * 512 + t * 2];
      a0 += (float)v[0];
      a1 += (float)v[1];
    }
  }
#pragma unroll
  for (int u = 0; u < 2; ++u) {
    int x = t * 2 + u;
    float a = u ? a1 : a0;
    int dst;
    if (x < 128) {
      dst = x * 4;
    } else {
      int xm = x - 128;
      int c = xm >> 7, j = xm & 127;
      dst = j * 4 + 1 + c;
    }
    os[dst] = a;
  }
  __syncthreads();
  *(float2*)&out[(size_t)n * 512 + t * 2] = *(const float2*)&os[t * 2];
}

// ---------------------------------------------------------------------------
extern "C" void kernel_launch(void* const* d_in, const int* in_sizes, int n_in,
                              void* d_out, int out_size, void* d_ws, size_t ws_size,
                              hipStream_t stream) {
  const float* node_feats = (const float*)d_in[1];
  const float* edge_attrs = (const float*)d_in[2];
  const float* edge_feats = (const float*)d_in[3];
  const int*   edge_index = (const int*)d_in[4];
  const float* W_up0   = (const float*)d_in[5];
  const float* W_up1   = (const float*)d_in[6];
  const float* W_down  = (const float*)d_in[7];
  const float* Wm0     = (const float*)d_in[8];
  const float* Wm1     = (const float*)d_in[9];
  const float* Wm2     = (const float*)d_in[10];
  const float* Wm3     = (const float*)d_in[11];
  const float* W_lin0  = (const float*)d_in[12];
  const float* W_lin1  = (const float*)d_in[13];
  const float* W_skip0 = (const float*)d_in[14];
  const float* W_skip1 = (const float*)d_in[15];
  float* out = (float*)d_out;

  char* ws = (char*)d_ws;
  size_t off = 0;
  auto alloc = [&](size_t bytes) {
    void* p = ws + off;
    off = (off + bytes + 255) & ~(size_t)255;
    return p;
  };
  // Round-4/6 byte offsets restored for every buffer edge_mlp touches
  // (round-7's WS0h/WS1h/WDh insertion shifted CNTS..MIDs by ~272 KB and
  // coincided with edge_mlp's +48 us stall regression at identical
  // counters — L2 set-aliasing hypothesis; this round tests it with a
  // host-only change).
  _Float16* UPH   = (_Float16*)alloc((size_t)NN * 512 * 2);
  _Float16* DOWNH = (_Float16*)alloc((size_t)NN * 64 * 2);
  _Float16* W0h   = (_Float16*)alloc(160 * 256 * 2);
  _Float16* W1h   = (_Float16*)alloc(256 * 256 * 2);
  _Float16* W2h   = (_Float16*)alloc(256 * 256 * 2);
  _Float16* W3h   = (_Float16*)alloc(256 * 512 * 2);
  _Float16* WL0h  = (_Float16*)alloc(256 * 128 * 2);
  _Float16* WL1h  = (_Float16*)alloc(256 * 128 * 2);
  int*      CNTS  = (int*)alloc((size_t)2 * NN * 4);  // CNT | CNT2, one memset
  int*      CNT   = CNTS;
  int*      CNT2  = CNTS + NN;
  int*      OFF   = (int*)alloc((size_t)(NN + 1) * 4);
  int*      CUR   = (int*)alloc((size_t)NN * 4);
  int*      EIDX  = (int*)alloc((size_t)NE * 4);
  int*      OFF2  = (int*)alloc((size_t)(NN + 1) * 4);
  int*      CUR2  = (int*)alloc((size_t)NN * 4);
  int*      SIDX  = (int*)alloc((size_t)NE * 4);
  _Float16* MIDs  = (_Float16*)alloc((size_t)NE * 512 * 2);
  // new buffers AFTER MIDs (tail of workspace)
  _Float16* WS0h  = (_Float16*)alloc(128 * 256 * 2);  // [Wup0|Wskip0]
  _Float16* WS1h  = (_Float16*)alloc(128 * 256 * 2);  // [Wup1|Wskip1]
  _Float16* WDh   = (_Float16*)alloc(128 * 64 * 2);   // Wdown

  hipMemsetAsync(CNTS, 0, (size_t)2 * NN * 4, stream);

  // wconv9 = 9 weight conversions (1056 blocks) + edge counting (625).
  wconv9<<<1681, 256, 0, stream>>>(Wm0, Wm1, Wm2, Wm3, W_lin0, W_lin1,
                                   W0h, W1h, W2h, W3h, WL0h, WL1h,
                                   W_up0, W_skip0, W_up1, W_skip1, W_down,
                                   WS0h, WS1h, WDh,
                                   edge_index, CNT, CNT2);

  // node pre-pass as MFMA GEMMs (157 s-blocks + 469 v-blocks)
  prep2<<<626, 256, 0, stream>>>(node_feats, WS0h, WS1h, WDh,
                                 UPH, DOWNH, out + (size_t)NN * 512);

  k_scan2<<<2, 1024, 0, stream>>>(CNT, OFF, CUR, CNT2, OFF2, CUR2);
  k_fill2<<<625, 256, 0, stream>>>(edge_index, CUR, EIDX, CUR2, SIDX);

  edge_mlp<<<2500, 256, 0, stream>>>(edge_attrs, edge_feats, edge_index, SIDX,
                                     DOWNH, UPH, W0h, W1h, W2h, W3h, WL0h, WL1h,
                                     MIDs);
  gather_msg<<<NN, 256, 0, stream>>>(MIDs, OFF, EIDX, out);
}